// Round 9
// baseline (203.715 us; speedup 1.0000x reference)
//
#include <hip/hip_runtime.h>
#include <math.h>

#define TT 2048
#define DMODEL 512
#define NHEADS 8
#define DHEAD 64
#define NBATCH 2
#define MTOK (NBATCH*TT)
#define NSPLIT 4
#define SC 0.18033688011112042f   // 0.125 * log2(e): fold 1/sqrt(Dh) and exp->exp2

typedef unsigned short u16;
typedef unsigned int u32;
typedef __bf16 bf16x8 __attribute__((ext_vector_type(8)));
typedef float f32x4 __attribute__((ext_vector_type(4)));
typedef short s16x4 __attribute__((ext_vector_type(4)));
typedef short s16x8 __attribute__((ext_vector_type(8)));
typedef int s32x4 __attribute__((ext_vector_type(4)));

#define MFMA16(a,b,c) __builtin_amdgcn_mfma_f32_16x16x32_bf16(a,b,c,0,0,0)
#define MFMA_PV(a,b,c) __builtin_amdgcn_mfma_f32_16x16x16bf16_1k(a,b,c,0,0,0)

__device__ __forceinline__ u16 f2b(float f){
  u32 x = __float_as_uint(f);
  x = x + 0x7fffu + ((x >> 16) & 1u);
  return (u16)(x >> 16);
}
__device__ __forceinline__ float b2f(u16 u){
  return __uint_as_float(((u32)u) << 16);
}
__device__ __forceinline__ u32 cvtpk(float lo, float hi){
  u32 d; asm("v_cvt_pk_bf16_f32 %0, %1, %2" : "=v"(d) : "v"(lo), "v"(hi)); return d;
}
// MFMA fragment layout index (16-row x 32-col tiles, lane*8 contiguous per wave):
__device__ __forceinline__ size_t fidx(int t, int d){
  return ((size_t)((t>>4)*16 + (d>>5)))*512
       + (size_t)(((((d>>3)&3)*16) + (t&15))*8 + (d&7));
}

// ---------------- weight prep: ws = mean|W| + 1e-5, ternary Wt (fragment layout) ----------------
__global__ __launch_bounds__(256) void wprep1_kernel(
    const float* __restrict__ W0, const float* __restrict__ W1,
    const float* __restrict__ W2, const float* __restrict__ W3,
    const float* __restrict__ W4, float* __restrict__ partial)
{
  int widx = blockIdx.y;
  const float* W = (widx==0)?W0:(widx==1)?W1:(widx==2)?W2:(widx==3)?W3:W4;
  size_t base = (size_t)blockIdx.x * 4096;
  int tid = threadIdx.x;
  float s = 0.f;
  for (int i = tid; i < 4096; i += 256) s += fabsf(W[base + i]);
  __shared__ float red[256];
  red[tid] = s; __syncthreads();
  for (int o = 128; o > 0; o >>= 1){ if (tid < o) red[tid] += red[tid+o]; __syncthreads(); }
  if (tid == 0) partial[widx*64 + blockIdx.x] = red[0];
}

__global__ __launch_bounds__(256) void wprep2_kernel(
    const float* __restrict__ W0, const float* __restrict__ W1,
    const float* __restrict__ W2, const float* __restrict__ W3,
    const float* __restrict__ W4, const float* __restrict__ partial,
    float* __restrict__ wsv, u16* __restrict__ wt)
{
  int widx = blockIdx.y;
  const float* W = (widx==0)?W0:(widx==1)?W1:(widx==2)?W2:(widx==3)?W3:W4;
  __shared__ float red[64];
  int tid = threadIdx.x;
  if (tid < 64) red[tid] = partial[widx*64 + tid];
  __syncthreads();
  for (int o = 32; o > 0; o >>= 1){ if (tid < o) red[tid] += red[tid+o]; __syncthreads(); }
  float ws = red[0] * (1.0f/262144.0f) + 1e-5f;
  if (blockIdx.x == 0 && tid == 0) wsv[widx] = ws;
  int base = blockIdx.x * 1024;
  for (int i = tid; i < 1024; i += 256){
    int idx = base + i;
    int n = idx >> 9, k = idx & 511;
    float v = rintf(W[idx] / ws);
    v = fminf(fmaxf(v, -1.f), 1.f);
    wt[(size_t)widx*262144 + fidx(n, k)] = f2b(v);
  }
}

// ---------------- LayerNorm + activation quant (per token, fragment-layout output) ----------------
__global__ __launch_bounds__(256) void lnq_kernel(
    const float* __restrict__ x, const float* __restrict__ g, const float* __restrict__ b,
    const int* __restrict__ bwp, u16* __restrict__ xq, float* __restrict__ stok)
{
  int t = blockIdx.x;
  const float* xr = x + (size_t)t * DMODEL;
  int tid = threadIdx.x;
  float v0 = xr[tid], v1 = xr[tid + 256];
  __shared__ float red[256];
  red[tid] = v0 + v1; __syncthreads();
  for (int o=128;o>0;o>>=1){ if(tid<o) red[tid]+=red[tid+o]; __syncthreads(); }
  float mu = red[0] * (1.0f/512.0f);
  __syncthreads();
  float d0 = v0 - mu, d1 = v1 - mu;
  red[tid] = d0*d0 + d1*d1; __syncthreads();
  for (int o=128;o>0;o>>=1){ if(tid<o) red[tid]+=red[tid+o]; __syncthreads(); }
  float var = red[0] * (1.0f/512.0f);
  __syncthreads();
  float rs = rsqrtf(var + 1e-5f);
  float y0 = d0*rs*g[tid] + b[tid];
  float y1 = d1*rs*g[tid+256] + b[tid+256];
  red[tid] = fmaxf(fabsf(y0), fabsf(y1)); __syncthreads();
  for (int o=128;o>0;o>>=1){ if(tid<o) red[tid]=fmaxf(red[tid],red[tid+o]); __syncthreads(); }
  float amax = red[0];
  float Qb = (float)((1 << (bwp[0]-1)) - 1);
  float xs = Qb / (amax + 1e-5f);
  if (tid == 0) stok[t] = (amax + 1e-5f) / Qb;
  float q0 = fminf(fmaxf(rintf(y0 * xs), -Qb), Qb);
  float q1 = fminf(fmaxf(rintf(y1 * xs), -Qb), Qb);
  xq[fidx(t, tid)]       = f2b(q0);
  xq[fidx(t, tid + 256)] = f2b(q1);
}

// ---------------- activation quant only (per token, fragment-layout output) ----------------
__global__ __launch_bounds__(256) void quant_kernel(
    const float* __restrict__ src, const int* __restrict__ bwp,
    u16* __restrict__ xq, float* __restrict__ stok)
{
  int t = blockIdx.x;
  const float* xr = src + (size_t)t * DMODEL;
  int tid = threadIdx.x;
  float v0 = xr[tid], v1 = xr[tid + 256];
  __shared__ float red[256];
  red[tid] = fmaxf(fabsf(v0), fabsf(v1)); __syncthreads();
  for (int o=128;o>0;o>>=1){ if(tid<o) red[tid]=fmaxf(red[tid],red[tid+o]); __syncthreads(); }
  float amax = red[0];
  float Qb = (float)((1 << (bwp[0]-1)) - 1);
  float xs = Qb / (amax + 1e-5f);
  if (tid == 0) stok[t] = (amax + 1e-5f) / Qb;
  float q0 = fminf(fmaxf(rintf(v0 * xs), -Qb), Qb);
  float q1 = fminf(fmaxf(rintf(v1 * xs), -Qb), Qb);
  xq[fidx(t, tid)]       = f2b(q0);
  xq[fidx(t, tid + 256)] = f2b(q1);
}

// ---------------- mask row flags: 1 if whole row nonzero ----------------
__global__ __launch_bounds__(256) void maskflag_kernel(const int* __restrict__ mask, int* __restrict__ rowflag){
  int row = blockIdx.x; // b*TT + q
  int tid = threadIdx.x;
  int ok = 1;
  const int* mr = mask + (size_t)row * TT;
  for (int i = tid; i < TT; i += 256) ok &= (mr[i] != 0);
  __shared__ int red[256];
  red[tid] = ok; __syncthreads();
  for (int o=128;o>0;o>>=1){ if(tid<o) red[tid] &= red[tid+o]; __syncthreads(); }
  if (tid == 0) rowflag[row] = red[0];
}

// ---------------- merged QKV quantized GEMM (N = 1536 over concat Wq|Wk|Wv, coalesced fragments) ----------------
__global__ __launch_bounds__(256) void qkvgemm_kernel(
    const u16* __restrict__ Af, const u16* __restrict__ wtf,
    const float* __restrict__ stok, const float* __restrict__ wsv,
    const float* __restrict__ bq, const float* __restrict__ bk, const float* __restrict__ bv,
    const float* __restrict__ pbu, const float* __restrict__ pbv,
    u16* __restrict__ Qu, u16* __restrict__ Qv, u16* __restrict__ Kf, u16* __restrict__ Vf)
{
  int w = threadIdx.x >> 6, lane = threadIdx.x & 63;
  int g = lane >> 4, li = lane & 15;
  int mb = blockIdx.y*64 + w*16;
  int nb = blockIdx.x*64;           // 0..1535, widx constant per block
  int widx = nb >> 9;
  int ntb = (nb & 511) >> 4;
  f32x4 acc[4] = {{0,0,0,0},{0,0,0,0},{0,0,0,0},{0,0,0,0}};
  const u16* Ab = Af + (size_t)(mb >> 4)*16*512 + lane*8;
  const u16* Bb = wtf + (size_t)widx*262144 + (size_t)ntb*16*512 + lane*8;
  for (int kb = 0; kb < 16; kb++){
    bf16x8 a = *(const bf16x8*)(Ab + kb*512);
#pragma unroll
    for (int f = 0; f < 4; f++){
      bf16x8 bb = *(const bf16x8*)(Bb + (f*16 + kb)*512);
      acc[f] = MFMA16(a, bb, acc[f]);
    }
  }
  float ws = wsv[widx];
  const float* bias = (widx==0)?bq:(widx==1)?bk:bv;
  float sc[4];
#pragma unroll
  for (int r=0;r<4;r++) sc[r] = ws * stok[mb + 4*g + r];
#pragma unroll
  for (int f=0;f<4;f++){
    int n = nb + 16*f + li;
    int nq = n & 511;
    float bn = bias[nq];
#pragma unroll
    for (int r=0;r<4;r++){
      int m = mb + 4*g + r;
      float val = acc[f][r]*sc[r] + bn;
      int bb_ = m >> 11, t = m & (TT-1); int h = nq >> 6, d = nq & 63;
      int bh = bb_*NHEADS + h;
      if (widx == 0){
        size_t o = (((size_t)bh)*TT + t)*DHEAD + d;
        Qu[o] = f2b((val + pbu[nq])*SC);
        Qv[o] = f2b(val + pbv[nq]);
      } else if (widx == 1){
        size_t o = (((size_t)bh*128 + (t>>4))*2 + (d>>5))*512
                 + (size_t)((((d>>3)&3)*16 + (t&15))*8 + (d&7));
        Kf[o] = f2b(val);
      } else {
        size_t o = (((size_t)bh*128 + (t>>4))*2 + (d>>5))*512
                 + (size_t)(((((t>>2)&3)*16) + (d&15))*8 + (((d>>4)&1)*4) + (t&3));
        Vf[o] = f2b(val);
      }
    }
  }
}

// ---------------- quantized GEMM (narrow tiles, NF cols of 16 per wave, coalesced fragments) ----------------
// modes: 3=P -> Pf fragment layout (Kf-style, per head)   4=O->f32 d_out = x + val*maskrow
template<int NF>
__global__ __launch_bounds__(256) void qgemm_kernel(
    const u16* __restrict__ Af, const u16* __restrict__ Wtf,
    const float* __restrict__ stok, const float* __restrict__ wsv, int widx,
    const float* __restrict__ bias, int mode,
    u16* __restrict__ outA, float* __restrict__ outF,
    const float* __restrict__ xin, const int* __restrict__ mask)
{
  int w = threadIdx.x >> 6, lane = threadIdx.x & 63;
  int g = lane >> 4, li = lane & 15;
  int mb = blockIdx.y*64 + w*16;
  int nb = blockIdx.x*(16*NF);
  f32x4 acc[NF];
#pragma unroll
  for (int f=0; f<NF; f++) acc[f] = (f32x4){0,0,0,0};
  const u16* Ab = Af + (size_t)(mb >> 4)*16*512 + lane*8;
  const u16* Bb = Wtf + (size_t)(nb >> 4)*16*512 + lane*8;
  for (int kb = 0; kb < 16; kb++){
    bf16x8 a = *(const bf16x8*)(Ab + kb*512);
#pragma unroll
    for (int f = 0; f < NF; f++){
      bf16x8 bb = *(const bf16x8*)(Bb + (f*16 + kb)*512);
      acc[f] = MFMA16(a, bb, acc[f]);
    }
  }
  float ws = wsv[widx];
  float sc[4];
#pragma unroll
  for (int r=0;r<4;r++) sc[r] = ws * stok[mb + 4*g + r];
#pragma unroll
  for (int f=0;f<NF;f++){
    int n = nb + 16*f + li;
    float bn = bias[n];
#pragma unroll
    for (int r=0;r<4;r++){
      int m = mb + 4*g + r;
      float val = acc[f][r]*sc[r] + bn;
      if (mode == 3){
        int h = n >> 6, d = n & 63;
        size_t o = (((size_t)h*128 + (m>>4))*2 + (d>>5))*512
                 + (size_t)((((d>>3)&3)*16 + (m&15))*8 + (d&7));
        outA[o] = f2b(val);
      } else {
        int bb_ = m >> 11, t = m & (TT-1);
        float mv = (float)mask[((size_t)bb_*TT + t)*TT];
        outF[(size_t)m*DMODEL + n] = xin[(size_t)m*DMODEL + n] + val*mv;
      }
    }
  }
}

// ---------------- split-K flash attention with FUSED rel-pos bd (no bd materialization) ----------------
// bd_s[q][k] = Qv[q]·p[k+2047-q] (k<=q) | Qv[q+1]·p[k-q-2] (k>=q+2) | 0 (k==q+1), all *SC.
// Per 128-k super-tile: batched bd phase (mfma(A=P, B=Qv): lane li owns q=qt+li, register r walks k)
// into a per-lane-private XOR-swizzled LDS row (no barriers; per-wave DS is in-order), then two
// 64-k flash tiles consume it. Swizzle slot^((li&7)<<2) keeps f32x4 reads aligned, <=2-way banks.
__global__ __launch_bounds__(256) void flash_kernel(
    const u16* __restrict__ Qu, const u16* __restrict__ Qv,
    const u16* __restrict__ Kf, const u16* __restrict__ Vf,
    const u16* __restrict__ Pf,
    const int* __restrict__ mask, const int* __restrict__ rowflag,
    u16* __restrict__ Opart, float* __restrict__ Mpart, float* __restrict__ Lpart)
{
  __shared__ float bdl[64*128];   // 32 KB: row = 16w+li (per-lane private), 128 k-slots swizzled
  int w = threadIdx.x >> 6, lane = threadIdx.x & 63;
  int g = lane >> 4, li = lane & 15;
  int bh = blockIdx.y; int b = bh >> 3, h = bh & 7;
  int z = blockIdx.z;
  int qb = blockIdx.x*64;
  int qt = qb + 16*w;
  int q  = qt + li;
  int rowbase = (16*w + li)*128;
  int swz = (li & 7) << 2;

  const u16* qrow = Qu + ((size_t)bh*TT + q)*DHEAD;
  bf16x8 qu0 = *(const bf16x8*)(qrow + 8*g);
  bf16x8 qu1 = *(const bf16x8*)(qrow + 32 + 8*g);
  const u16* vr0 = Qv + ((size_t)bh*TT + q)*DHEAD;
  bf16x8 qv00 = *(const bf16x8*)(vr0 + 8*g);
  bf16x8 qv01 = *(const bf16x8*)(vr0 + 32 + 8*g);
  int q1 = (q < TT-1) ? (q+1) : (TT-1);
  const u16* vr1 = Qv + ((size_t)bh*TT + q1)*DHEAD;
  bf16x8 qv10 = *(const bf16x8*)(vr1 + 8*g);
  bf16x8 qv11 = *(const bf16x8*)(vr1 + 32 + 8*g);

  f32x4 acc[4] = {{0,0,0,0},{0,0,0,0},{0,0,0,0},{0,0,0,0}};
  float mrun = -3e38f, lrun = 0.f;
  int rf = rowflag[b*TT + q];
  bool needmask = (__all(rf) == 0);

  const u16* kfb = Kf + (size_t)bh*128*1024;
  const u16* vfb = Vf + (size_t)bh*128*1024;
  const u16* Pl  = Pf + (size_t)h*128*1024 + lane*8;
  const int* maskq = mask + ((size_t)b*TT + q)*TT;

  int kofs_lo = 4*g - (2047 - qt - li);   // slot = jt + kofs_lo - ks + r  (lower)
  int kofs_up = 4*g + qt + li + 2;        // slot = jt + kofs_up - ks + r  (upper)

  int kbeg = z * (TT/NSPLIT);
  for (int ks = kbeg; ks < kbeg + TT/NSPLIT; ks += 128){
    // ======== bd phase: fill slots [0,128) of this lane's row ========
    {
      // lower triangle (k <= q): j-window for 128 k
      int JL0 = (ks + 2032 - qt) & ~15;
      int jl1 = (ks + 2174 - qt) & ~15;
      int JL1 = (jl1 < 2032) ? jl1 : 2032;
      for (int jt = JL0; jt <= JL1; jt += 16){
        const u16* pp = Pl + jt*64;
        f32x4 c = {0,0,0,0};
        c = MFMA16(*(const bf16x8*)(pp),       qv00, c);
        c = MFMA16(*(const bf16x8*)(pp + 512), qv01, c);
        int sbase = jt + kofs_lo - ks;
#pragma unroll
        for (int r = 0; r < 4; r++){
          int s_ = sbase + r;
          if ((unsigned)s_ < 128u) bdl[rowbase + (s_ ^ swz)] = c[r]*SC;
        }
      }
      // upper triangle (k >= q+2)
      int ju0 = (ks - qt - 17) & ~15;
      int JU0 = (ju0 > 0) ? ju0 : 0;
      int ju1 = (ks + 125 - qt) & ~15;
      int JU1 = (ju1 < 2032) ? ju1 : 2032;
      for (int jt = JU0; jt <= JU1; jt += 16){
        const u16* pp = Pl + jt*64;
        f32x4 c = {0,0,0,0};
        c = MFMA16(*(const bf16x8*)(pp),       qv10, c);
        c = MFMA16(*(const bf16x8*)(pp + 512), qv11, c);
        int sbase = jt + kofs_up - ks;
#pragma unroll
        for (int r = 0; r < 4; r++){
          int s_ = sbase + r;
          if ((unsigned)s_ < 128u) bdl[rowbase + (s_ ^ swz)] = c[r]*SC;
        }
      }
      // diagonal k == q+1 is exactly zero
      int kd = q + 1 - ks;
      if ((unsigned)kd < 128u) bdl[rowbase + (kd ^ swz)] = 0.f;
    }
    // ======== flash phase: two 64-k tiles ========
#pragma unroll
    for (int sub = 0; sub < 2; sub++){
      int k0 = ks + 64*sub;
      int kb = k0 >> 4;
      f32x4 s[4];
#pragma unroll
      for (int kc = 0; kc < 4; kc++){
        const u16* kp = kfb + (size_t)(kb + kc)*1024 + lane*8;
        f32x4 t_ = {0,0,0,0};
        t_ = MFMA16(*(const bf16x8*)(kp),       qu0, t_);
        t_ = MFMA16(*(const bf16x8*)(kp + 512), qu1, t_);
        s[kc] = t_;
      }
#pragma unroll
      for (int kc = 0; kc < 4; kc++){
        f32x4 bd4 = *(const f32x4*)(&bdl[rowbase + ((64*sub + 16*kc + 4*g) ^ swz)]);
#pragma unroll
        for (int r = 0; r < 4; r++) s[kc][r] += bd4[r];
      }
      if (needmask && !rf){
#pragma unroll
        for (int kc = 0; kc < 4; kc++){
          s32x4 mv = *(const s32x4*)(maskq + k0 + 16*kc + 4*g);
#pragma unroll
          for (int r = 0; r < 4; r++)
            if (mv[r] == 0) s[kc][r] = -3e38f;
        }
      }
      float tm = s[0][0];
#pragma unroll
      for (int kc = 0; kc < 4; kc++)
#pragma unroll
        for (int r = 0; r < 4; r++) tm = fmaxf(tm, s[kc][r]);
      tm = fmaxf(tm, __shfl_xor(tm, 16));
      tm = fmaxf(tm, __shfl_xor(tm, 32));
      float mn;
      if (__all(tm <= mrun)){
        mn = mrun;
      } else {
        mn = fmaxf(mrun, tm);
        float fscq = __builtin_amdgcn_exp2f(mrun - mn);
        mrun = mn;
        lrun *= fscq;
#pragma unroll
        for (int r = 0; r < 4; r++){
          float fr = __shfl(fscq, 4*g + r);
          acc[0][r] *= fr; acc[1][r] *= fr; acc[2][r] *= fr; acc[3][r] *= fr;
        }
      }
      float ps = 0.f;
      s16x4 pk[4];
#pragma unroll
      for (int kc = 0; kc < 4; kc++){
        float p0 = __builtin_amdgcn_exp2f(s[kc][0] - mn);
        float p1 = __builtin_amdgcn_exp2f(s[kc][1] - mn);
        float p2 = __builtin_amdgcn_exp2f(s[kc][2] - mn);
        float p3 = __builtin_amdgcn_exp2f(s[kc][3] - mn);
        ps += (p0 + p1) + (p2 + p3);
        union { u32 w[2]; s16x4 v; } u_;
        u_.w[0] = cvtpk(p0, p1);
        u_.w[1] = cvtpk(p2, p3);
        pk[kc] = u_.v;
      }
      ps += __shfl_xor(ps, 16);
      ps += __shfl_xor(ps, 32);
      lrun += ps;
#pragma unroll
      for (int kc = 0; kc < 4; kc++){
        const u16* vp = vfb + (size_t)(kb + kc)*1024 + lane*8;
        bf16x8 v0 = *(const bf16x8*)(vp);
        bf16x8 v1 = *(const bf16x8*)(vp + 512);
        s16x8 w0 = (s16x8)v0, w1 = (s16x8)v1;
        acc[0] = MFMA_PV(pk[kc], __builtin_shufflevector(w0, w0, 0,1,2,3), acc[0]);
        acc[1] = MFMA_PV(pk[kc], __builtin_shufflevector(w0, w0, 4,5,6,7), acc[1]);
        acc[2] = MFMA_PV(pk[kc], __builtin_shufflevector(w1, w1, 0,1,2,3), acc[2]);
        acc[3] = MFMA_PV(pk[kc], __builtin_shufflevector(w1, w1, 4,5,6,7), acc[3]);
      }
    }
  }
  // store unnormalized partials
#pragma unroll
  for (int r = 0; r < 4; r++){
    size_t o = ((size_t)(b*TT + qt + 4*g + r)*NSPLIT + z)*DMODEL + h*DHEAD + li;
    Opart[o]      = f2b(acc[0][r]);
    Opart[o + 16] = f2b(acc[1][r]);
    Opart[o + 32] = f2b(acc[2][r]);
    Opart[o + 48] = f2b(acc[3][r]);
  }
  if (lane < 16){
    size_t mo = ((size_t)(b*TT + qt + li)*NSPLIT + z)*NHEADS + h;
    Mpart[mo] = mrun;
    Lpart[mo] = lrun;
  }
}

// ---------------- merge splits + per-token absmax quant of H (fragment-layout output) ----------------
__global__ __launch_bounds__(256) void merge_kernel(
    const u16* __restrict__ Opart, const float* __restrict__ Mpart, const float* __restrict__ Lpart,
    const int* __restrict__ bwp, u16* __restrict__ xq, float* __restrict__ stok)
{
  int tok = blockIdx.x, tid = threadIdx.x;
  __shared__ float scl[NSPLIT][NHEADS];
  if (tid < NHEADS){
    int h = tid;
    float ms[NSPLIT], ls[NSPLIT];
#pragma unroll
    for (int s = 0; s < NSPLIT; s++){
      ms[s] = Mpart[((size_t)tok*NSPLIT + s)*NHEADS + h];
      ls[s] = Lpart[((size_t)tok*NSPLIT + s)*NHEADS + h];
    }
    float mst = ms[0];
#pragma unroll
    for (int s = 1; s < NSPLIT; s++) mst = fmaxf(mst, ms[s]);
    float sc_[NSPLIT]; float lst = 0.f;
#pragma unroll
    for (int s = 0; s < NSPLIT; s++){
      sc_[s] = __builtin_amdgcn_exp2f(ms[s] - mst);
      lst += ls[s]*sc_[s];
    }
    float inv = (lst > 0.f) ? 1.0f/lst : 0.f;
#pragma unroll
    for (int s = 0; s < NSPLIT; s++) scl[s][h] = sc_[s]*inv;
  }
  __syncthreads();
  float hv[2];
#pragma unroll
  for (int j = 0; j < 2; j++){
    int idx = tid + 256*j;
    int h = idx >> 6;
    float a = 0.f;
#pragma unroll
    for (int s = 0; s < NSPLIT; s++)
      a += b2f(Opart[((size_t)tok*NSPLIT + s)*DMODEL + idx]) * scl[s][h];
    hv[j] = a;
  }
  __shared__ float red[256];
  red[tid] = fmaxf(fabsf(hv[0]), fabsf(hv[1])); __syncthreads();
  for (int o=128;o>0;o>>=1){ if(tid<o) red[tid]=fmaxf(red[tid],red[tid+o]); __syncthreads(); }
  float amax = red[0];
  float Qb = (float)((1 << (bwp[0]-1)) - 1);
  float xs = Qb / (amax + 1e-5f);
  if (tid == 0) stok[tok] = (amax + 1e-5f) / Qb;
#pragma unroll
  for (int j = 0; j < 2; j++){
    int idx = tid + 256*j;
    float qv = fminf(fmaxf(rintf(hv[j] * xs), -Qb), Qb);
    xq[fidx(tok, idx)] = f2b(qv);
  }
}

// ---------------- launch ----------------
extern "C" void kernel_launch(void* const* d_in, const int* in_sizes, int n_in,
                              void* d_out, int out_size, void* d_ws, size_t ws_size,
                              hipStream_t stream) {
  const float* x    = (const float*)d_in[0];
  const int*   mask = (const int*)  d_in[1];
  const float* pos  = (const float*)d_in[2];
  const float* lng  = (const float*)d_in[3];
  const float* lnb  = (const float*)d_in[4];
  const float* Wq   = (const float*)d_in[5];
  const float* bq   = (const float*)d_in[6];
  const float* Wk   = (const float*)d_in[7];
  const float* bk   = (const float*)d_in[8];
  const float* Wv   = (const float*)d_in[9];
  const float* bv   = (const float*)d_in[10];
  const float* Wp   = (const float*)d_in[11];
  const float* bp   = (const float*)d_in[12];
  const float* Wo   = (const float*)d_in[13];
  const float* bo   = (const float*)d_in[14];
  const float* pbu  = (const float*)d_in[15];
  const float* pbv  = (const float*)d_in[16];
  const int*   bwp  = (const int*)  d_in[17];
  float* out = (float*)d_out;

  char* wsb = (char*)d_ws;
  size_t off = 0;
  auto alloc = [&](size_t nbytes)->char* {
    char* p = wsb + off;
    off = (off + nbytes + 255) & ~(size_t)255;
    return p;
  };
  float* partial = (float*)alloc(5*64*sizeof(float));
  float* wsv     = (float*)alloc(5*sizeof(float));
  u16*   wt      = (u16*)  alloc((size_t)5*262144*2);
  float* stok_y  = (float*)alloc(MTOK*sizeof(float));
  float* stok_p  = (float*)alloc(TT*sizeof(float));
  u16*   Qu      = (u16*)  alloc((size_t)16*TT*DHEAD*2);
  u16*   Qv      = (u16*)  alloc((size_t)16*TT*DHEAD*2);
  u16*   Kf      = (u16*)  alloc((size_t)16*TT*DHEAD*2);
  u16*   Vf      = (u16*)  alloc((size_t)16*TT*DHEAD*2);
  u16*   Pf      = (u16*)  alloc((size_t)NHEADS*TT*DHEAD*2);   // live during flash: own alloc
  // pool: xq_y + xq_p live before flash; Opart (aliased) live after
  u16*   pool    = (u16*)  alloc((size_t)MTOK*NSPLIT*DMODEL*2);   // 16.8 MB
  u16*   xq_y    = pool;
  u16*   xq_p    = pool + (size_t)MTOK*DMODEL;
  u16*   Opart   = pool;
  float* Mpart   = (float*)alloc((size_t)MTOK*NSPLIT*NHEADS*sizeof(float));
  float* Lpart   = (float*)alloc((size_t)MTOK*NSPLIT*NHEADS*sizeof(float));
  u16*   xq_H    = (u16*)  alloc((size_t)MTOK*DMODEL*2);
  float* stok_H  = (float*)alloc(MTOK*sizeof(float));
  int*   rowflag = (int*)  alloc(MTOK*sizeof(int));
  if (off > ws_size) return;  // clean fail if workspace too small

  // weight prep
  wprep1_kernel<<<dim3(64,5), 256, 0, stream>>>(Wq, Wk, Wv, Wp, Wo, partial);
  wprep2_kernel<<<dim3(256,5), 256, 0, stream>>>(Wq, Wk, Wv, Wp, Wo, partial, wsv, wt);
  // activations
  lnq_kernel<<<MTOK, 256, 0, stream>>>(x, lng, lnb, bwp, xq_y, stok_y);
  quant_kernel<<<TT, 256, 0, stream>>>(pos, bwp, xq_p, stok_p);
  maskflag_kernel<<<MTOK, 256, 0, stream>>>(mask, rowflag);
  // projections: merged QKV, then P (fragment layout)
  qkvgemm_kernel<<<dim3(24,64), 256, 0, stream>>>(xq_y, wt, stok_y, wsv, bq, bk, bv, pbu, pbv,
                                                  Qu, Qv, Kf, Vf);
  qgemm_kernel<2><<<dim3(16,32), 256, 0, stream>>>(xq_p, wt + (size_t)3*262144, stok_p, wsv, 3, bp, 3,
                                                   Pf, nullptr, nullptr, nullptr);
  // fused attention (bd computed in-kernel, batched per 128-k super-tile), split-K
  flash_kernel<<<dim3(32,16,NSPLIT), 256, 0, stream>>>(Qu, Qv, Kf, Vf, Pf, mask, rowflag,
                                                       Opart, Mpart, Lpart);
  // merge splits + quantize H
  merge_kernel<<<MTOK, 256, 0, stream>>>(Opart, Mpart, Lpart, bwp, xq_H, stok_H);
  // output projection (+ residual + seq mask)
  qgemm_kernel<2><<<dim3(16,64), 256, 0, stream>>>(xq_H, wt + (size_t)4*262144, stok_H, wsv, 4, bo, 4,
                                                   nullptr, out, x, mask);
}

// Round 10
// 182.066 us; speedup vs baseline: 1.1189x; 1.1189x over previous
//
#include <hip/hip_runtime.h>
#include <math.h>

#define TT 2048
#define DMODEL 512
#define NHEADS 8
#define DHEAD 64
#define NBATCH 2
#define MTOK (NBATCH*TT)
#define NSPLIT 4
#define SC 0.18033688011112042f   // 0.125 * log2(e): fold 1/sqrt(Dh) and exp->exp2
#define PADQ 68                   // LDS row pad (f32 words): 16B-aligned rows, spread banks

typedef unsigned short u16;
typedef unsigned int u32;
typedef __bf16 bf16x8 __attribute__((ext_vector_type(8)));
typedef float f32x4 __attribute__((ext_vector_type(4)));
typedef float f32x2 __attribute__((ext_vector_type(2)));
typedef short s16x4 __attribute__((ext_vector_type(4)));
typedef short s16x8 __attribute__((ext_vector_type(8)));
typedef unsigned short u16x4 __attribute__((ext_vector_type(4)));
typedef unsigned int u32x4 __attribute__((ext_vector_type(4)));
typedef int s32x4 __attribute__((ext_vector_type(4)));

#define MFMA16(a,b,c) __builtin_amdgcn_mfma_f32_16x16x32_bf16(a,b,c,0,0,0)
#define MFMA_PV(a,b,c) __builtin_amdgcn_mfma_f32_16x16x16bf16_1k(a,b,c,0,0,0)

__device__ __forceinline__ u16 f2b(float f){
  u32 x = __float_as_uint(f);
  x = x + 0x7fffu + ((x >> 16) & 1u);
  return (u16)(x >> 16);
}
__device__ __forceinline__ float b2f(u16 u){
  return __uint_as_float(((u32)u) << 16);
}
__device__ __forceinline__ u32 cvtpk(float lo, float hi){
  u32 d; asm("v_cvt_pk_bf16_f32 %0, %1, %2" : "=v"(d) : "v"(lo), "v"(hi)); return d;
}
// fp8 e4m3 (OCP) pack/unpack via HW converts
__device__ __forceinline__ u32 pk4fp8(float a, float b, float c, float d){
  u32 lo, hi;
  asm("v_cvt_pk_fp8_f32 %0, %1, %2" : "=v"(lo) : "v"(a), "v"(b));
  asm("v_cvt_pk_fp8_f32 %0, %1, %2" : "=v"(hi) : "v"(c), "v"(d));
  return (lo & 0xFFFFu) | (hi << 16);
}
__device__ __forceinline__ f32x2 upk2fp8(u32 v){
  f32x2 r;
  asm("v_cvt_pk_f32_fp8 %0, %1" : "=v"(r) : "v"(v));
  return r;
}
// MFMA fragment layout index (16-row x 32-col tiles, lane*8 contiguous per wave):
__device__ __forceinline__ size_t fidx(int t, int d){
  return ((size_t)((t>>4)*16 + (d>>5)))*512
       + (size_t)(((((d>>3)&3)*16) + (t&15))*8 + (d&7));
}

// ---------------- weight prep: ws = mean|W| + 1e-5, ternary Wt (fragment layout) ----------------
__global__ __launch_bounds__(256) void wprep1_kernel(
    const float* __restrict__ W0, const float* __restrict__ W1,
    const float* __restrict__ W2, const float* __restrict__ W3,
    const float* __restrict__ W4, float* __restrict__ partial)
{
  int widx = blockIdx.y;
  const float* W = (widx==0)?W0:(widx==1)?W1:(widx==2)?W2:(widx==3)?W3:W4;
  size_t base = (size_t)blockIdx.x * 4096;
  int tid = threadIdx.x;
  float s = 0.f;
  for (int i = tid; i < 4096; i += 256) s += fabsf(W[base + i]);
  __shared__ float red[256];
  red[tid] = s; __syncthreads();
  for (int o = 128; o > 0; o >>= 1){ if (tid < o) red[tid] += red[tid+o]; __syncthreads(); }
  if (tid == 0) partial[widx*64 + blockIdx.x] = red[0];
}

__global__ __launch_bounds__(256) void wprep2_kernel(
    const float* __restrict__ W0, const float* __restrict__ W1,
    const float* __restrict__ W2, const float* __restrict__ W3,
    const float* __restrict__ W4, const float* __restrict__ partial,
    float* __restrict__ wsv, u16* __restrict__ wt)
{
  int widx = blockIdx.y;
  const float* W = (widx==0)?W0:(widx==1)?W1:(widx==2)?W2:(widx==3)?W3:W4;
  __shared__ float red[64];
  int tid = threadIdx.x;
  if (tid < 64) red[tid] = partial[widx*64 + tid];
  __syncthreads();
  for (int o = 32; o > 0; o >>= 1){ if (tid < o) red[tid] += red[tid+o]; __syncthreads(); }
  float ws = red[0] * (1.0f/262144.0f) + 1e-5f;
  if (blockIdx.x == 0 && tid == 0) wsv[widx] = ws;
  int base = blockIdx.x * 1024;
  for (int i = tid; i < 1024; i += 256){
    int idx = base + i;
    int n = idx >> 9, k = idx & 511;
    float v = rintf(W[idx] / ws);
    v = fminf(fmaxf(v, -1.f), 1.f);
    wt[(size_t)widx*262144 + fidx(n, k)] = f2b(v);
  }
}

// ---------------- LayerNorm + activation quant (per token, fragment-layout output) ----------------
__global__ __launch_bounds__(256) void lnq_kernel(
    const float* __restrict__ x, const float* __restrict__ g, const float* __restrict__ b,
    const int* __restrict__ bwp, u16* __restrict__ xq, float* __restrict__ stok)
{
  int t = blockIdx.x;
  const float* xr = x + (size_t)t * DMODEL;
  int tid = threadIdx.x;
  float v0 = xr[tid], v1 = xr[tid + 256];
  __shared__ float red[256];
  red[tid] = v0 + v1; __syncthreads();
  for (int o=128;o>0;o>>=1){ if(tid<o) red[tid]+=red[tid+o]; __syncthreads(); }
  float mu = red[0] * (1.0f/512.0f);
  __syncthreads();
  float d0 = v0 - mu, d1 = v1 - mu;
  red[tid] = d0*d0 + d1*d1; __syncthreads();
  for (int o=128;o>0;o>>=1){ if(tid<o) red[tid]+=red[tid+o]; __syncthreads(); }
  float var = red[0] * (1.0f/512.0f);
  __syncthreads();
  float rs = rsqrtf(var + 1e-5f);
  float y0 = d0*rs*g[tid] + b[tid];
  float y1 = d1*rs*g[tid+256] + b[tid+256];
  red[tid] = fmaxf(fabsf(y0), fabsf(y1)); __syncthreads();
  for (int o=128;o>0;o>>=1){ if(tid<o) red[tid]=fmaxf(red[tid],red[tid+o]); __syncthreads(); }
  float amax = red[0];
  float Qb = (float)((1 << (bwp[0]-1)) - 1);
  float xs = Qb / (amax + 1e-5f);
  if (tid == 0) stok[t] = (amax + 1e-5f) / Qb;
  float q0 = fminf(fmaxf(rintf(y0 * xs), -Qb), Qb);
  float q1 = fminf(fmaxf(rintf(y1 * xs), -Qb), Qb);
  xq[fidx(t, tid)]       = f2b(q0);
  xq[fidx(t, tid + 256)] = f2b(q1);
}

// ---------------- activation quant only (per token, fragment-layout output) ----------------
__global__ __launch_bounds__(256) void quant_kernel(
    const float* __restrict__ src, const int* __restrict__ bwp,
    u16* __restrict__ xq, float* __restrict__ stok)
{
  int t = blockIdx.x;
  const float* xr = src + (size_t)t * DMODEL;
  int tid = threadIdx.x;
  float v0 = xr[tid], v1 = xr[tid + 256];
  __shared__ float red[256];
  red[tid] = fmaxf(fabsf(v0), fabsf(v1)); __syncthreads();
  for (int o=128;o>0;o>>=1){ if(tid<o) red[tid]=fmaxf(red[tid],red[tid+o]); __syncthreads(); }
  float amax = red[0];
  float Qb = (float)((1 << (bwp[0]-1)) - 1);
  float xs = Qb / (amax + 1e-5f);
  if (tid == 0) stok[t] = (amax + 1e-5f) / Qb;
  float q0 = fminf(fmaxf(rintf(v0 * xs), -Qb), Qb);
  float q1 = fminf(fmaxf(rintf(v1 * xs), -Qb), Qb);
  xq[fidx(t, tid)]       = f2b(q0);
  xq[fidx(t, tid + 256)] = f2b(q1);
}

// ---------------- mask row flags: 1 if whole row nonzero ----------------
__global__ __launch_bounds__(256) void maskflag_kernel(const int* __restrict__ mask, int* __restrict__ rowflag){
  int row = blockIdx.x; // b*TT + q
  int tid = threadIdx.x;
  int ok = 1;
  const int* mr = mask + (size_t)row * TT;
  for (int i = tid; i < TT; i += 256) ok &= (mr[i] != 0);
  __shared__ int red[256];
  red[tid] = ok; __syncthreads();
  for (int o=128;o>0;o>>=1){ if(tid<o) red[tid] &= red[tid+o]; __syncthreads(); }
  if (tid == 0) rowflag[row] = red[0];
}

// ---------------- merged QKV quantized GEMM (N = 1536 over concat Wq|Wk|Wv, coalesced fragments) ----------------
__global__ __launch_bounds__(256) void qkvgemm_kernel(
    const u16* __restrict__ Af, const u16* __restrict__ wtf,
    const float* __restrict__ stok, const float* __restrict__ wsv,
    const float* __restrict__ bq, const float* __restrict__ bk, const float* __restrict__ bv,
    const float* __restrict__ pbu, const float* __restrict__ pbv,
    u16* __restrict__ Qu, u16* __restrict__ Qv, u16* __restrict__ Kf, u16* __restrict__ Vf)
{
  int w = threadIdx.x >> 6, lane = threadIdx.x & 63;
  int g = lane >> 4, li = lane & 15;
  int mb = blockIdx.y*64 + w*16;
  int nb = blockIdx.x*64;           // 0..1535, widx constant per block
  int widx = nb >> 9;
  int ntb = (nb & 511) >> 4;
  f32x4 acc[4] = {{0,0,0,0},{0,0,0,0},{0,0,0,0},{0,0,0,0}};
  const u16* Ab = Af + (size_t)(mb >> 4)*16*512 + lane*8;
  const u16* Bb = wtf + (size_t)widx*262144 + (size_t)ntb*16*512 + lane*8;
  for (int kb = 0; kb < 16; kb++){
    bf16x8 a = *(const bf16x8*)(Ab + kb*512);
#pragma unroll
    for (int f = 0; f < 4; f++){
      bf16x8 bb = *(const bf16x8*)(Bb + (f*16 + kb)*512);
      acc[f] = MFMA16(a, bb, acc[f]);
    }
  }
  float ws = wsv[widx];
  const float* bias = (widx==0)?bq:(widx==1)?bk:bv;
  float sc[4];
#pragma unroll
  for (int r=0;r<4;r++) sc[r] = ws * stok[mb + 4*g + r];
#pragma unroll
  for (int f=0;f<4;f++){
    int n = nb + 16*f + li;
    int nq = n & 511;
    float bn = bias[nq];
#pragma unroll
    for (int r=0;r<4;r++){
      int m = mb + 4*g + r;
      float val = acc[f][r]*sc[r] + bn;
      int bb_ = m >> 11, t = m & (TT-1); int h = nq >> 6, d = nq & 63;
      int bh = bb_*NHEADS + h;
      if (widx == 0){
        size_t o = (((size_t)bh)*TT + t)*DHEAD + d;
        Qu[o] = f2b((val + pbu[nq])*SC);
        Qv[o] = f2b(val + pbv[nq]);
      } else if (widx == 1){
        size_t o = (((size_t)bh*128 + (t>>4))*2 + (d>>5))*512
                 + (size_t)((((d>>3)&3)*16 + (t&15))*8 + (d&7));
        Kf[o] = f2b(val);
      } else {
        size_t o = (((size_t)bh*128 + (t>>4))*2 + (d>>5))*512
                 + (size_t)(((((t>>2)&3)*16) + (d&15))*8 + (((d>>4)&1)*4) + (t&3));
        Vf[o] = f2b(val);
      }
    }
  }
}

// ---------------- quantized GEMM (narrow tiles, NF cols of 16 per wave, coalesced fragments) ----------------
// modes: 3=P -> Pf fragment layout (Kf-style, per head)   4=O->f32 d_out = x + val*maskrow
template<int NF>
__global__ __launch_bounds__(256) void qgemm_kernel(
    const u16* __restrict__ Af, const u16* __restrict__ Wtf,
    const float* __restrict__ stok, const float* __restrict__ wsv, int widx,
    const float* __restrict__ bias, int mode,
    u16* __restrict__ outA, float* __restrict__ outF,
    const float* __restrict__ xin, const int* __restrict__ mask)
{
  int w = threadIdx.x >> 6, lane = threadIdx.x & 63;
  int g = lane >> 4, li = lane & 15;
  int mb = blockIdx.y*64 + w*16;
  int nb = blockIdx.x*(16*NF);
  f32x4 acc[NF];
#pragma unroll
  for (int f=0; f<NF; f++) acc[f] = (f32x4){0,0,0,0};
  const u16* Ab = Af + (size_t)(mb >> 4)*16*512 + lane*8;
  const u16* Bb = Wtf + (size_t)(nb >> 4)*16*512 + lane*8;
  for (int kb = 0; kb < 16; kb++){
    bf16x8 a = *(const bf16x8*)(Ab + kb*512);
#pragma unroll
    for (int f = 0; f < NF; f++){
      bf16x8 bb = *(const bf16x8*)(Bb + (f*16 + kb)*512);
      acc[f] = MFMA16(a, bb, acc[f]);
    }
  }
  float ws = wsv[widx];
  float sc[4];
#pragma unroll
  for (int r=0;r<4;r++) sc[r] = ws * stok[mb + 4*g + r];
#pragma unroll
  for (int f=0;f<NF;f++){
    int n = nb + 16*f + li;
    float bn = bias[n];
#pragma unroll
    for (int r=0;r<4;r++){
      int m = mb + 4*g + r;
      float val = acc[f][r]*sc[r] + bn;
      if (mode == 3){
        int h = n >> 6, d = n & 63;
        size_t o = (((size_t)h*128 + (m>>4))*2 + (d>>5))*512
                 + (size_t)((((d>>3)&3)*16 + (m&15))*8 + (d&7));
        outA[o] = f2b(val);
      } else {
        int bb_ = m >> 11, t = m & (TT-1);
        float mv = (float)mask[((size_t)bb_*TT + t)*TT];
        outF[(size_t)m*DMODEL + n] = xin[(size_t)m*DMODEL + n] + val*mv;
      }
    }
  }
}

// ---------------- bd kernel: output-tiled rel-shifted GEMM, f32 LDS transpose, fp8 lined writes ----------------
// bd_s[q][k] = R[q][k+TT-1-q] (k<=q) | R[q+1][k-q-2] (k>=q+2) | 0 (k==q+1); values *SC.
// VALU-trimmed: f32 LDS (no bf16 round-trip), no full zeroing (coverage proof: every (q,k') slot is
// written by exactly one of {lower loop, upper loop, explicit diagonal} -- loop break conditions are
// exactly the no-lane-in-range conditions). fp8 packed straight from f32 at writeout.
__global__ __launch_bounds__(256) void bd_kernel(
    const u16* __restrict__ Qv, const u16* __restrict__ Pf, u32* __restrict__ bdq)
{
  __shared__ float lds[64*PADQ];
  int tid = threadIdx.x;
  int w = tid >> 6, lane = tid & 63;
  int g = lane >> 4, li = lane & 15;
  int bh = blockIdx.z, h = bh & 7;
  int qb = blockIdx.y*64, k0 = blockIdx.x*64;
  int qt = qb + 16*w;
  // diagonal k == q+1 (the only slot neither triangle writes)
  if (tid < 64){
    int kd = qb + tid + 1 - k0;
    if ((unsigned)kd < 64u) lds[kd*PADQ + tid] = 0.f;
  }
  const u16* Pbh = Pf + (size_t)h*128*1024;
  const u16* Qbh = Qv + (size_t)bh*TT*DHEAD;
  int qp = 16*w + 4*g;
  // ---- lower triangle: bd_s[q][k] = R[q][j], j = k + TT-1 - q ----
  {
    const u16* qr = Qbh + (size_t)(qt + li)*DHEAD;
    bf16x8 a0 = *(const bf16x8*)(qr + 8*g);
    bf16x8 a1 = *(const bf16x8*)(qr + 32 + 8*g);
    int dkq = k0 - qt;
    for (int i = 0; i < 5; i++){
      if (dkq + 16*i > 15) break;
      int jt = k0 + TT - 16 - qt + 16*i;
      int j = jt + li;
      bool jok = (j <= TT-1);
      int jc = jok ? j : (TT-1);
      const u16* pr = Pbh + (size_t)(jc>>4)*1024 + (size_t)((g*16 + (jc&15))*8);
      f32x4 c = {0,0,0,0};
      c = MFMA16(a0, *(const bf16x8*)(pr),       c);
      c = MFMA16(a1, *(const bf16x8*)(pr + 512), c);
      int kp = 16*i - 15 + li + 4*g;
#pragma unroll
      for (int r = 0; r < 4; r++){
        int kpr = kp + r;
        if (jok && kpr >= 0 && kpr < 64)
          lds[kpr*PADQ + qp + r] = c[r]*SC;
      }
    }
  }
  // ---- upper triangle: bd_s[q][k] = R[q+1][j2], j2 = k - q - 2 ----
  {
    int q2r = qt + 1 + li; if (q2r > TT-1) q2r = TT-1;
    const u16* qr = Qbh + (size_t)q2r*DHEAD;
    bf16x8 a0 = *(const bf16x8*)(qr + 8*g);
    bf16x8 a1 = *(const bf16x8*)(qr + 32 + 8*g);
    int dqk = qt - k0;
    for (int i = 5; i >= 0; i--){
      if (16*i < dqk + 17) break;
      int jt2 = k0 - qt - 32 + 16*i;
      int j2 = jt2 + li;
      bool jok = (j2 >= 0);
      int jc = jok ? j2 : 0;
      const u16* pr = Pbh + (size_t)(jc>>4)*1024 + (size_t)((g*16 + (jc&15))*8);
      f32x4 c = {0,0,0,0};
      c = MFMA16(a0, *(const bf16x8*)(pr),       c);
      c = MFMA16(a1, *(const bf16x8*)(pr + 512), c);
      int kp = 16*i - 30 + li + 4*g;
#pragma unroll
      for (int r = 0; r < 4; r++){
        int kpr = kp + r;
        if (jok && kpr >= 0 && kpr < 64)
          lds[kpr*PADQ + qp + r] = c[r]*SC;
      }
    }
  }
  __syncthreads();
  // ---- writeout: fp8-pack from f32, bdq[k>>2][q], contiguous 256B runs per 16-thread group ----
  {
    int kq = tid >> 4, qg = tid & 15;
    f32x4 v[4];
#pragma unroll
    for (int kk = 0; kk < 4; kk++)
      v[kk] = *(const f32x4*)(&lds[(4*kq + kk)*PADQ + 4*qg]);
    u32x4 o4;
#pragma unroll
    for (int qq = 0; qq < 4; qq++)
      o4[qq] = pk4fp8(v[0][qq], v[1][qq], v[2][qq], v[3][qq]);
    u32* ob = bdq + (size_t)bh*(TT/4)*TT + ((size_t)((k0>>2) + kq)*TT + qb + 4*qg);
    *(u32x4*)ob = o4;
  }
}

// ---------------- split-K flash attention (coalesced fragment layouts, fp8 bd, zero-LDS, zero-barrier) ----------------
__global__ __launch_bounds__(256) void flash_kernel(
    const u16* __restrict__ Qu, const u16* __restrict__ Kf,
    const u16* __restrict__ Vf, const u32* __restrict__ bdq,
    const int* __restrict__ mask, const int* __restrict__ rowflag,
    u16* __restrict__ Opart, float* __restrict__ Mpart, float* __restrict__ Lpart)
{
  int w = threadIdx.x >> 6, lane = threadIdx.x & 63;
  int g = lane >> 4, li = lane & 15;
  int bh = blockIdx.y; int b = bh >> 3, h = bh & 7;
  int z = blockIdx.z;
  int qb = blockIdx.x*64 + w*16;
  int q = qb + li;

  const u16* qrow = Qu + ((size_t)bh*TT + q)*DHEAD;
  bf16x8 qu0 = *(const bf16x8*)(qrow + 8*g);
  bf16x8 qu1 = *(const bf16x8*)(qrow + 32 + 8*g);

  f32x4 acc[4] = {{0,0,0,0},{0,0,0,0},{0,0,0,0},{0,0,0,0}};
  float mrun = -3e38f, lrun = 0.f;
  int rf = rowflag[b*TT + q];
  bool needmask = (__all(rf) == 0);

  const u16* kfb = Kf + (size_t)bh*128*1024;
  const u16* vfb = Vf + (size_t)bh*128*1024;
  const u32* bdb = bdq + (size_t)bh*(TT/4)*TT;
  const int* maskq = mask + ((size_t)b*TT + q)*TT;

  int kbeg = z * (TT/NSPLIT);
  for (int k0 = kbeg; k0 < kbeg + TT/NSPLIT; k0 += 64){
    int kb = k0 >> 4;
    f32x4 s[4];
#pragma unroll
    for (int kc = 0; kc < 4; kc++){
      const u16* kp = kfb + (size_t)(kb + kc)*1024 + lane*8;
      f32x4 t_ = {0,0,0,0};
      t_ = MFMA16(*(const bf16x8*)(kp),       qu0, t_);
      t_ = MFMA16(*(const bf16x8*)(kp + 512), qu1, t_);
      s[kc] = t_;
    }
#pragma unroll
    for (int kc = 0; kc < 4; kc++){
      u32 wb = bdb[(size_t)((k0>>2) + 4*kc + g)*TT + q];
      f32x2 lo2 = upk2fp8(wb);
      f32x2 hi2 = upk2fp8(wb >> 16);
      s[kc][0] += lo2[0]; s[kc][1] += lo2[1];
      s[kc][2] += hi2[0]; s[kc][3] += hi2[1];
    }
    if (needmask && !rf){
#pragma unroll
      for (int kc = 0; kc < 4; kc++){
        s32x4 mv = *(const s32x4*)(maskq + k0 + 16*kc + 4*g);
#pragma unroll
        for (int r = 0; r < 4; r++)
          if (mv[r] == 0) s[kc][r] = -3e38f;
      }
    }
    float tm = s[0][0];
#pragma unroll
    for (int kc = 0; kc < 4; kc++)
#pragma unroll
      for (int r = 0; r < 4; r++) tm = fmaxf(tm, s[kc][r]);
    tm = fmaxf(tm, __shfl_xor(tm, 16));
    tm = fmaxf(tm, __shfl_xor(tm, 32));
    float mn;
    if (__all(tm <= mrun)){
      mn = mrun;
    } else {
      mn = fmaxf(mrun, tm);
      float fscq = __builtin_amdgcn_exp2f(mrun - mn);
      mrun = mn;
      lrun *= fscq;
#pragma unroll
      for (int r = 0; r < 4; r++){
        float fr = __shfl(fscq, 4*g + r);
        acc[0][r] *= fr; acc[1][r] *= fr; acc[2][r] *= fr; acc[3][r] *= fr;
      }
    }
    float ps = 0.f;
    s16x4 pk[4];
#pragma unroll
    for (int kc = 0; kc < 4; kc++){
      float p0 = __builtin_amdgcn_exp2f(s[kc][0] - mn);
      float p1 = __builtin_amdgcn_exp2f(s[kc][1] - mn);
      float p2 = __builtin_amdgcn_exp2f(s[kc][2] - mn);
      float p3 = __builtin_amdgcn_exp2f(s[kc][3] - mn);
      ps += (p0 + p1) + (p2 + p3);
      union { u32 w[2]; s16x4 v; } u_;
      u_.w[0] = cvtpk(p0, p1);
      u_.w[1] = cvtpk(p2, p3);
      pk[kc] = u_.v;
    }
    ps += __shfl_xor(ps, 16);
    ps += __shfl_xor(ps, 32);
    lrun += ps;
#pragma unroll
    for (int kc = 0; kc < 4; kc++){
      const u16* vp = vfb + (size_t)(kb + kc)*1024 + lane*8;
      bf16x8 v0 = *(const bf16x8*)(vp);
      bf16x8 v1 = *(const bf16x8*)(vp + 512);
      s16x8 w0 = (s16x8)v0, w1 = (s16x8)v1;
      acc[0] = MFMA_PV(pk[kc], __builtin_shufflevector(w0, w0, 0,1,2,3), acc[0]);
      acc[1] = MFMA_PV(pk[kc], __builtin_shufflevector(w0, w0, 4,5,6,7), acc[1]);
      acc[2] = MFMA_PV(pk[kc], __builtin_shufflevector(w1, w1, 0,1,2,3), acc[2]);
      acc[3] = MFMA_PV(pk[kc], __builtin_shufflevector(w1, w1, 4,5,6,7), acc[3]);
    }
  }
#pragma unroll
  for (int r = 0; r < 4; r++){
    size_t o = ((size_t)(b*TT + qb + 4*g + r)*NSPLIT + z)*DMODEL + h*DHEAD + li;
    Opart[o]      = f2b(acc[0][r]);
    Opart[o + 16] = f2b(acc[1][r]);
    Opart[o + 32] = f2b(acc[2][r]);
    Opart[o + 48] = f2b(acc[3][r]);
  }
  if (lane < 16){
    size_t mo = ((size_t)(b*TT + qb + li)*NSPLIT + z)*NHEADS + h;
    Mpart[mo] = mrun;
    Lpart[mo] = lrun;
  }
}

// ---------------- merge splits + per-token absmax quant of H (fragment-layout output) ----------------
__global__ __launch_bounds__(256) void merge_kernel(
    const u16* __restrict__ Opart, const float* __restrict__ Mpart, const float* __restrict__ Lpart,
    const int* __restrict__ bwp, u16* __restrict__ xq, float* __restrict__ stok)
{
  int tok = blockIdx.x, tid = threadIdx.x;
  __shared__ float scl[NSPLIT][NHEADS];
  if (tid < NHEADS){
    int h = tid;
    float ms[NSPLIT], ls[NSPLIT];
#pragma unroll
    for (int s = 0; s < NSPLIT; s++){
      ms[s] = Mpart[((size_t)tok*NSPLIT + s)*NHEADS + h];
      ls[s] = Lpart[((size_t)tok*NSPLIT + s)*NHEADS + h];
    }
    float mst = ms[0];
#pragma unroll
    for (int s = 1; s < NSPLIT; s++) mst = fmaxf(mst, ms[s]);
    float sc_[NSPLIT]; float lst = 0.f;
#pragma unroll
    for (int s = 0; s < NSPLIT; s++){
      sc_[s] = __builtin_amdgcn_exp2f(ms[s] - mst);
      lst += ls[s]*sc_[s];
    }
    float inv = (lst > 0.f) ? 1.0f/lst : 0.f;
#pragma unroll
    for (int s = 0; s < NSPLIT; s++) scl[s][h] = sc_[s]*inv;
  }
  __syncthreads();
  float hv[2];
#pragma unroll
  for (int j = 0; j < 2; j++){
    int idx = tid + 256*j;
    int h = idx >> 6;
    float a = 0.f;
#pragma unroll
    for (int s = 0; s < NSPLIT; s++)
      a += b2f(Opart[((size_t)tok*NSPLIT + s)*DMODEL + idx]) * scl[s][h];
    hv[j] = a;
  }
  __shared__ float red[256];
  red[tid] = fmaxf(fabsf(hv[0]), fabsf(hv[1])); __syncthreads();
  for (int o=128;o>0;o>>=1){ if(tid<o) red[tid]=fmaxf(red[tid],red[tid+o]); __syncthreads(); }
  float amax = red[0];
  float Qb = (float)((1 << (bwp[0]-1)) - 1);
  float xs = Qb / (amax + 1e-5f);
  if (tid == 0) stok[tok] = (amax + 1e-5f) / Qb;
#pragma unroll
  for (int j = 0; j < 2; j++){
    int idx = tid + 256*j;
    float qv = fminf(fmaxf(rintf(hv[j] * xs), -Qb), Qb);
    xq[fidx(tok, idx)] = f2b(qv);
  }
}

// ---------------- launch ----------------
extern "C" void kernel_launch(void* const* d_in, const int* in_sizes, int n_in,
                              void* d_out, int out_size, void* d_ws, size_t ws_size,
                              hipStream_t stream) {
  const float* x    = (const float*)d_in[0];
  const int*   mask = (const int*)  d_in[1];
  const float* pos  = (const float*)d_in[2];
  const float* lng  = (const float*)d_in[3];
  const float* lnb  = (const float*)d_in[4];
  const float* Wq   = (const float*)d_in[5];
  const float* bq   = (const float*)d_in[6];
  const float* Wk   = (const float*)d_in[7];
  const float* bk   = (const float*)d_in[8];
  const float* Wv   = (const float*)d_in[9];
  const float* bv   = (const float*)d_in[10];
  const float* Wp   = (const float*)d_in[11];
  const float* bp   = (const float*)d_in[12];
  const float* Wo   = (const float*)d_in[13];
  const float* bo   = (const float*)d_in[14];
  const float* pbu  = (const float*)d_in[15];
  const float* pbv  = (const float*)d_in[16];
  const int*   bwp  = (const int*)  d_in[17];
  float* out = (float*)d_out;

  char* wsb = (char*)d_ws;
  size_t off = 0;
  auto alloc = [&](size_t nbytes)->char* {
    char* p = wsb + off;
    off = (off + nbytes + 255) & ~(size_t)255;
    return p;
  };
  float* partial = (float*)alloc(5*64*sizeof(float));
  float* wsv     = (float*)alloc(5*sizeof(float));
  u16*   wt      = (u16*)  alloc((size_t)5*262144*2);
  float* stok_y  = (float*)alloc(MTOK*sizeof(float));
  float* stok_p  = (float*)alloc(TT*sizeof(float));
  u16*   Qu      = (u16*)  alloc((size_t)16*TT*DHEAD*2);
  u16*   Qv      = (u16*)  alloc((size_t)16*TT*DHEAD*2);
  u16*   Kf      = (u16*)  alloc((size_t)16*TT*DHEAD*2);
  u16*   Vf      = (u16*)  alloc((size_t)16*TT*DHEAD*2);
  // pool: xq_y + xq_p + Pf live before flash; Opart (aliased) live after
  u16*   pool    = (u16*)  alloc((size_t)MTOK*NSPLIT*DMODEL*2);   // 16.8 MB
  u16*   xq_y    = pool;
  u16*   xq_p    = pool + (size_t)MTOK*DMODEL;
  u16*   Pf      = xq_p + (size_t)TT*DMODEL;
  u16*   Opart   = pool;
  float* Mpart   = (float*)alloc((size_t)MTOK*NSPLIT*NHEADS*sizeof(float));
  float* Lpart   = (float*)alloc((size_t)MTOK*NSPLIT*NHEADS*sizeof(float));
  u16*   xq_H    = (u16*)  alloc((size_t)MTOK*DMODEL*2);
  float* stok_H  = (float*)alloc(MTOK*sizeof(float));
  int*   rowflag = (int*)  alloc(MTOK*sizeof(int));
  u32*   bdq     = (u32*)  alloc((size_t)16*(TT/4)*TT*4);         // 67 MB fp8-packed
  if (off > ws_size) return;  // clean fail if workspace too small

  // weight prep
  wprep1_kernel<<<dim3(64,5), 256, 0, stream>>>(Wq, Wk, Wv, Wp, Wo, partial);
  wprep2_kernel<<<dim3(256,5), 256, 0, stream>>>(Wq, Wk, Wv, Wp, Wo, partial, wsv, wt);
  // activations
  lnq_kernel<<<MTOK, 256, 0, stream>>>(x, lng, lnb, bwp, xq_y, stok_y);
  quant_kernel<<<TT, 256, 0, stream>>>(pos, bwp, xq_p, stok_p);
  maskflag_kernel<<<MTOK, 256, 0, stream>>>(mask, rowflag);
  // projections: merged QKV, then P (fragment layout)
  qkvgemm_kernel<<<dim3(24,64), 256, 0, stream>>>(xq_y, wt, stok_y, wsv, bq, bk, bv, pbu, pbv,
                                                  Qu, Qv, Kf, Vf);
  qgemm_kernel<2><<<dim3(16,32), 256, 0, stream>>>(xq_p, wt + (size_t)3*262144, stok_p, wsv, 3, bp, 3,
                                                   Pf, nullptr, nullptr, nullptr);
  // rel-pos matrix: output-tiled, f32 LDS transpose, fp8-packed lined HBM writes
  bd_kernel<<<dim3(32,32,16), 256, 0, stream>>>(Qv, Pf, bdq);
  // fused attention, split-K
  flash_kernel<<<dim3(32,16,NSPLIT), 256, 0, stream>>>(Qu, Kf, Vf, bdq, mask, rowflag,
                                                       Opart, Mpart, Lpart);
  // merge splits + quantize H
  merge_kernel<<<MTOK, 256, 0, stream>>>(Opart, Mpart, Lpart, bwp, xq_H, stok_H);
  // output projection (+ residual + seq mask)
  qgemm_kernel<2><<<dim3(16,64), 256, 0, stream>>>(xq_H, wt + (size_t)4*262144, stok_H, wsv, 4, bo, 4,
                                                   nullptr, out, x, mask);
}

// Round 11
// 181.433 us; speedup vs baseline: 1.1228x; 1.0035x over previous
//
#include <hip/hip_runtime.h>
#include <math.h>

#define TT 2048
#define DMODEL 512
#define NHEADS 8
#define DHEAD 64
#define NBATCH 2
#define MTOK (NBATCH*TT)
#define NSPLIT 4
#define SC 0.18033688011112042f   // 0.125 * log2(e): fold 1/sqrt(Dh) and exp->exp2
#define PADQ 68                   // LDS row pad (f32 words): 16B-aligned rows, spread banks

typedef unsigned short u16;
typedef unsigned int u32;
typedef __bf16 bf16x8 __attribute__((ext_vector_type(8)));
typedef float f32x4 __attribute__((ext_vector_type(4)));
typedef float f32x2 __attribute__((ext_vector_type(2)));
typedef short s16x4 __attribute__((ext_vector_type(4)));
typedef short s16x8 __attribute__((ext_vector_type(8)));
typedef unsigned short u16x4 __attribute__((ext_vector_type(4)));
typedef unsigned int u32x4 __attribute__((ext_vector_type(4)));
typedef int s32x4 __attribute__((ext_vector_type(4)));

#define MFMA16(a,b,c) __builtin_amdgcn_mfma_f32_16x16x32_bf16(a,b,c,0,0,0)
#define MFMA_PV(a,b,c) __builtin_amdgcn_mfma_f32_16x16x16bf16_1k(a,b,c,0,0,0)

__device__ __forceinline__ u16 f2b(float f){
  u32 x = __float_as_uint(f);
  x = x + 0x7fffu + ((x >> 16) & 1u);
  return (u16)(x >> 16);
}
__device__ __forceinline__ float b2f(u16 u){
  return __uint_as_float(((u32)u) << 16);
}
__device__ __forceinline__ u32 cvtpk(float lo, float hi){
  u32 d; asm("v_cvt_pk_bf16_f32 %0, %1, %2" : "=v"(d) : "v"(lo), "v"(hi)); return d;
}
// fp8 e4m3 (OCP) pack/unpack via HW converts
__device__ __forceinline__ u32 pk4fp8(float a, float b, float c, float d){
  u32 lo, hi;
  asm("v_cvt_pk_fp8_f32 %0, %1, %2" : "=v"(lo) : "v"(a), "v"(b));
  asm("v_cvt_pk_fp8_f32 %0, %1, %2" : "=v"(hi) : "v"(c), "v"(d));
  return (lo & 0xFFFFu) | (hi << 16);
}
__device__ __forceinline__ f32x2 upk2fp8(u32 v){
  f32x2 r;
  asm("v_cvt_pk_f32_fp8 %0, %1" : "=v"(r) : "v"(v));
  return r;
}
// MFMA fragment layout index (16-row x 32-col tiles, lane*8 contiguous per wave):
__device__ __forceinline__ size_t fidx(int t, int d){
  return ((size_t)((t>>4)*16 + (d>>5)))*512
       + (size_t)(((((d>>3)&3)*16) + (t&15))*8 + (d&7));
}

// ---------------- weight prep: ws = mean|W| + 1e-5, ternary Wt (fragment layout) ----------------
__global__ __launch_bounds__(256) void wprep1_kernel(
    const float* __restrict__ W0, const float* __restrict__ W1,
    const float* __restrict__ W2, const float* __restrict__ W3,
    const float* __restrict__ W4, float* __restrict__ partial)
{
  int widx = blockIdx.y;
  const float* W = (widx==0)?W0:(widx==1)?W1:(widx==2)?W2:(widx==3)?W3:W4;
  size_t base = (size_t)blockIdx.x * 4096;
  int tid = threadIdx.x;
  float s = 0.f;
  for (int i = tid; i < 4096; i += 256) s += fabsf(W[base + i]);
  __shared__ float red[256];
  red[tid] = s; __syncthreads();
  for (int o = 128; o > 0; o >>= 1){ if (tid < o) red[tid] += red[tid+o]; __syncthreads(); }
  if (tid == 0) partial[widx*64 + blockIdx.x] = red[0];
}

__global__ __launch_bounds__(256) void wprep2_kernel(
    const float* __restrict__ W0, const float* __restrict__ W1,
    const float* __restrict__ W2, const float* __restrict__ W3,
    const float* __restrict__ W4, const float* __restrict__ partial,
    float* __restrict__ wsv, u16* __restrict__ wt)
{
  int widx = blockIdx.y;
  const float* W = (widx==0)?W0:(widx==1)?W1:(widx==2)?W2:(widx==3)?W3:W4;
  __shared__ float red[64];
  int tid = threadIdx.x;
  if (tid < 64) red[tid] = partial[widx*64 + tid];
  __syncthreads();
  for (int o = 32; o > 0; o >>= 1){ if (tid < o) red[tid] += red[tid+o]; __syncthreads(); }
  float ws = red[0] * (1.0f/262144.0f) + 1e-5f;
  if (blockIdx.x == 0 && tid == 0) wsv[widx] = ws;
  int base = blockIdx.x * 1024;
  for (int i = tid; i < 1024; i += 256){
    int idx = base + i;
    int n = idx >> 9, k = idx & 511;
    float v = rintf(W[idx] / ws);
    v = fminf(fmaxf(v, -1.f), 1.f);
    wt[(size_t)widx*262144 + fidx(n, k)] = f2b(v);
  }
}

// ---------------- LayerNorm + activation quant (per token, fragment-layout output) ----------------
__global__ __launch_bounds__(256) void lnq_kernel(
    const float* __restrict__ x, const float* __restrict__ g, const float* __restrict__ b,
    const int* __restrict__ bwp, u16* __restrict__ xq, float* __restrict__ stok)
{
  int t = blockIdx.x;
  const float* xr = x + (size_t)t * DMODEL;
  int tid = threadIdx.x;
  float v0 = xr[tid], v1 = xr[tid + 256];
  __shared__ float red[256];
  red[tid] = v0 + v1; __syncthreads();
  for (int o=128;o>0;o>>=1){ if(tid<o) red[tid]+=red[tid+o]; __syncthreads(); }
  float mu = red[0] * (1.0f/512.0f);
  __syncthreads();
  float d0 = v0 - mu, d1 = v1 - mu;
  red[tid] = d0*d0 + d1*d1; __syncthreads();
  for (int o=128;o>0;o>>=1){ if(tid<o) red[tid]+=red[tid+o]; __syncthreads(); }
  float var = red[0] * (1.0f/512.0f);
  __syncthreads();
  float rs = rsqrtf(var + 1e-5f);
  float y0 = d0*rs*g[tid] + b[tid];
  float y1 = d1*rs*g[tid+256] + b[tid+256];
  red[tid] = fmaxf(fabsf(y0), fabsf(y1)); __syncthreads();
  for (int o=128;o>0;o>>=1){ if(tid<o) red[tid]=fmaxf(red[tid],red[tid+o]); __syncthreads(); }
  float amax = red[0];
  float Qb = (float)((1 << (bwp[0]-1)) - 1);
  float xs = Qb / (amax + 1e-5f);
  if (tid == 0) stok[t] = (amax + 1e-5f) / Qb;
  float q0 = fminf(fmaxf(rintf(y0 * xs), -Qb), Qb);
  float q1 = fminf(fmaxf(rintf(y1 * xs), -Qb), Qb);
  xq[fidx(t, tid)]       = f2b(q0);
  xq[fidx(t, tid + 256)] = f2b(q1);
}

// ---------------- activation quant only (per token, fragment-layout output) ----------------
__global__ __launch_bounds__(256) void quant_kernel(
    const float* __restrict__ src, const int* __restrict__ bwp,
    u16* __restrict__ xq, float* __restrict__ stok)
{
  int t = blockIdx.x;
  const float* xr = src + (size_t)t * DMODEL;
  int tid = threadIdx.x;
  float v0 = xr[tid], v1 = xr[tid + 256];
  __shared__ float red[256];
  red[tid] = fmaxf(fabsf(v0), fabsf(v1)); __syncthreads();
  for (int o=128;o>0;o>>=1){ if(tid<o) red[tid]=fmaxf(red[tid],red[tid+o]); __syncthreads(); }
  float amax = red[0];
  float Qb = (float)((1 << (bwp[0]-1)) - 1);
  float xs = Qb / (amax + 1e-5f);
  if (tid == 0) stok[t] = (amax + 1e-5f) / Qb;
  float q0 = fminf(fmaxf(rintf(v0 * xs), -Qb), Qb);
  float q1 = fminf(fmaxf(rintf(v1 * xs), -Qb), Qb);
  xq[fidx(t, tid)]       = f2b(q0);
  xq[fidx(t, tid + 256)] = f2b(q1);
}

// ---------------- mask row flags: 1 if whole row nonzero ----------------
__global__ __launch_bounds__(256) void maskflag_kernel(const int* __restrict__ mask, int* __restrict__ rowflag){
  int row = blockIdx.x; // b*TT + q
  int tid = threadIdx.x;
  int ok = 1;
  const int* mr = mask + (size_t)row * TT;
  for (int i = tid; i < TT; i += 256) ok &= (mr[i] != 0);
  __shared__ int red[256];
  red[tid] = ok; __syncthreads();
  for (int o=128;o>0;o>>=1){ if(tid<o) red[tid] &= red[tid+o]; __syncthreads(); }
  if (tid == 0) rowflag[row] = red[0];
}

// ---------------- merged QKV quantized GEMM (N = 1536 over concat Wq|Wk|Wv, coalesced fragments) ----------------
__global__ __launch_bounds__(256) void qkvgemm_kernel(
    const u16* __restrict__ Af, const u16* __restrict__ wtf,
    const float* __restrict__ stok, const float* __restrict__ wsv,
    const float* __restrict__ bq, const float* __restrict__ bk, const float* __restrict__ bv,
    const float* __restrict__ pbu, const float* __restrict__ pbv,
    u16* __restrict__ Qu, u16* __restrict__ Qv, u16* __restrict__ Kf, u16* __restrict__ Vf)
{
  int w = threadIdx.x >> 6, lane = threadIdx.x & 63;
  int g = lane >> 4, li = lane & 15;
  int mb = blockIdx.y*64 + w*16;
  int nb = blockIdx.x*64;           // 0..1535, widx constant per block
  int widx = nb >> 9;
  int ntb = (nb & 511) >> 4;
  f32x4 acc[4] = {{0,0,0,0},{0,0,0,0},{0,0,0,0},{0,0,0,0}};
  const u16* Ab = Af + (size_t)(mb >> 4)*16*512 + lane*8;
  const u16* Bb = wtf + (size_t)widx*262144 + (size_t)ntb*16*512 + lane*8;
  for (int kb = 0; kb < 16; kb++){
    bf16x8 a = *(const bf16x8*)(Ab + kb*512);
#pragma unroll
    for (int f = 0; f < 4; f++){
      bf16x8 bb = *(const bf16x8*)(Bb + (f*16 + kb)*512);
      acc[f] = MFMA16(a, bb, acc[f]);
    }
  }
  float ws = wsv[widx];
  const float* bias = (widx==0)?bq:(widx==1)?bk:bv;
  float sc[4];
#pragma unroll
  for (int r=0;r<4;r++) sc[r] = ws * stok[mb + 4*g + r];
#pragma unroll
  for (int f=0;f<4;f++){
    int n = nb + 16*f + li;
    int nq = n & 511;
    float bn = bias[nq];
#pragma unroll
    for (int r=0;r<4;r++){
      int m = mb + 4*g + r;
      float val = acc[f][r]*sc[r] + bn;
      int bb_ = m >> 11, t = m & (TT-1); int h = nq >> 6, d = nq & 63;
      int bh = bb_*NHEADS + h;
      if (widx == 0){
        size_t o = (((size_t)bh)*TT + t)*DHEAD + d;
        Qu[o] = f2b((val + pbu[nq])*SC);
        Qv[o] = f2b(val + pbv[nq]);
      } else if (widx == 1){
        size_t o = (((size_t)bh*128 + (t>>4))*2 + (d>>5))*512
                 + (size_t)((((d>>3)&3)*16 + (t&15))*8 + (d&7));
        Kf[o] = f2b(val);
      } else {
        size_t o = (((size_t)bh*128 + (t>>4))*2 + (d>>5))*512
                 + (size_t)(((((t>>2)&3)*16) + (d&15))*8 + (((d>>4)&1)*4) + (t&3));
        Vf[o] = f2b(val);
      }
    }
  }
}

// ---------------- quantized GEMM (narrow tiles, NF cols of 16 per wave, coalesced fragments) ----------------
// modes: 3=P -> Pf fragment layout (Kf-style, per head)   4=O->f32 d_out = x + val*maskrow
template<int NF>
__global__ __launch_bounds__(256) void qgemm_kernel(
    const u16* __restrict__ Af, const u16* __restrict__ Wtf,
    const float* __restrict__ stok, const float* __restrict__ wsv, int widx,
    const float* __restrict__ bias, int mode,
    u16* __restrict__ outA, float* __restrict__ outF,
    const float* __restrict__ xin, const int* __restrict__ mask)
{
  int w = threadIdx.x >> 6, lane = threadIdx.x & 63;
  int g = lane >> 4, li = lane & 15;
  int mb = blockIdx.y*64 + w*16;
  int nb = blockIdx.x*(16*NF);
  f32x4 acc[NF];
#pragma unroll
  for (int f=0; f<NF; f++) acc[f] = (f32x4){0,0,0,0};
  const u16* Ab = Af + (size_t)(mb >> 4)*16*512 + lane*8;
  const u16* Bb = Wtf + (size_t)(nb >> 4)*16*512 + lane*8;
  for (int kb = 0; kb < 16; kb++){
    bf16x8 a = *(const bf16x8*)(Ab + kb*512);
#pragma unroll
    for (int f = 0; f < NF; f++){
      bf16x8 bb = *(const bf16x8*)(Bb + (f*16 + kb)*512);
      acc[f] = MFMA16(a, bb, acc[f]);
    }
  }
  float ws = wsv[widx];
  float sc[4];
#pragma unroll
  for (int r=0;r<4;r++) sc[r] = ws * stok[mb + 4*g + r];
#pragma unroll
  for (int f=0;f<NF;f++){
    int n = nb + 16*f + li;
    float bn = bias[n];
#pragma unroll
    for (int r=0;r<4;r++){
      int m = mb + 4*g + r;
      float val = acc[f][r]*sc[r] + bn;
      if (mode == 3){
        int h = n >> 6, d = n & 63;
        size_t o = (((size_t)h*128 + (m>>4))*2 + (d>>5))*512
                 + (size_t)((((d>>3)&3)*16 + (m&15))*8 + (d&7));
        outA[o] = f2b(val);
      } else {
        int bb_ = m >> 11, t = m & (TT-1);
        float mv = (float)mask[((size_t)bb_*TT + t)*TT];
        outF[(size_t)m*DMODEL + n] = xin[(size_t)m*DMODEL + n] + val*mv;
      }
    }
  }
}

// ---------------- bd kernel: output-tiled rel-shifted GEMM, f32 LDS transpose, fp8 lined writes ----------------
__global__ __launch_bounds__(256) void bd_kernel(
    const u16* __restrict__ Qv, const u16* __restrict__ Pf, u32* __restrict__ bdq)
{
  __shared__ float lds[64*PADQ];
  int tid = threadIdx.x;
  int w = tid >> 6, lane = tid & 63;
  int g = lane >> 4, li = lane & 15;
  int bh = blockIdx.z, h = bh & 7;
  int qb = blockIdx.y*64, k0 = blockIdx.x*64;
  int qt = qb + 16*w;
  // diagonal k == q+1 (the only slot neither triangle writes)
  if (tid < 64){
    int kd = qb + tid + 1 - k0;
    if ((unsigned)kd < 64u) lds[kd*PADQ + tid] = 0.f;
  }
  const u16* Pbh = Pf + (size_t)h*128*1024;
  const u16* Qbh = Qv + (size_t)bh*TT*DHEAD;
  int qp = 16*w + 4*g;
  // ---- lower triangle: bd_s[q][k] = R[q][j], j = k + TT-1 - q ----
  {
    const u16* qr = Qbh + (size_t)(qt + li)*DHEAD;
    bf16x8 a0 = *(const bf16x8*)(qr + 8*g);
    bf16x8 a1 = *(const bf16x8*)(qr + 32 + 8*g);
    int dkq = k0 - qt;
    for (int i = 0; i < 5; i++){
      if (dkq + 16*i > 15) break;
      int jt = k0 + TT - 16 - qt + 16*i;
      int j = jt + li;
      bool jok = (j <= TT-1);
      int jc = jok ? j : (TT-1);
      const u16* pr = Pbh + (size_t)(jc>>4)*1024 + (size_t)((g*16 + (jc&15))*8);
      f32x4 c = {0,0,0,0};
      c = MFMA16(a0, *(const bf16x8*)(pr),       c);
      c = MFMA16(a1, *(const bf16x8*)(pr + 512), c);
      int kp = 16*i - 15 + li + 4*g;
#pragma unroll
      for (int r = 0; r < 4; r++){
        int kpr = kp + r;
        if (jok && kpr >= 0 && kpr < 64)
          lds[kpr*PADQ + qp + r] = c[r]*SC;
      }
    }
  }
  // ---- upper triangle: bd_s[q][k] = R[q+1][j2], j2 = k - q - 2 ----
  {
    int q2r = qt + 1 + li; if (q2r > TT-1) q2r = TT-1;
    const u16* qr = Qbh + (size_t)q2r*DHEAD;
    bf16x8 a0 = *(const bf16x8*)(qr + 8*g);
    bf16x8 a1 = *(const bf16x8*)(qr + 32 + 8*g);
    int dqk = qt - k0;
    for (int i = 5; i >= 0; i--){
      if (16*i < dqk + 17) break;
      int jt2 = k0 - qt - 32 + 16*i;
      int j2 = jt2 + li;
      bool jok = (j2 >= 0);
      int jc = jok ? j2 : 0;
      const u16* pr = Pbh + (size_t)(jc>>4)*1024 + (size_t)((g*16 + (jc&15))*8);
      f32x4 c = {0,0,0,0};
      c = MFMA16(a0, *(const bf16x8*)(pr),       c);
      c = MFMA16(a1, *(const bf16x8*)(pr + 512), c);
      int kp = 16*i - 30 + li + 4*g;
#pragma unroll
      for (int r = 0; r < 4; r++){
        int kpr = kp + r;
        if (jok && kpr >= 0 && kpr < 64)
          lds[kpr*PADQ + qp + r] = c[r]*SC;
      }
    }
  }
  __syncthreads();
  // ---- writeout: fp8-pack from f32, bdq[k>>2][q], contiguous 256B runs per 16-thread group ----
  {
    int kq = tid >> 4, qg = tid & 15;
    f32x4 v[4];
#pragma unroll
    for (int kk = 0; kk < 4; kk++)
      v[kk] = *(const f32x4*)(&lds[(4*kq + kk)*PADQ + 4*qg]);
    u32x4 o4;
#pragma unroll
    for (int qq = 0; qq < 4; qq++)
      o4[qq] = pk4fp8(v[0][qq], v[1][qq], v[2][qq], v[3][qq]);
    u32* ob = bdq + (size_t)bh*(TT/4)*TT + ((size_t)((k0>>2) + kq)*TT + qb + 4*qg);
    *(u32x4*)ob = o4;
  }
}

// ---------------- split-K flash attention (2-deep k-tile pipeline, fp8 bd, zero-LDS, zero-barrier) ----------------
// Per 128-k iteration: issue all 8 bdq loads (longest latency) + all 16 QK MFMAs up front,
// then two softmax+PV phases consume them -- tile B's memory is in flight under tile A's VALU.
__global__ __launch_bounds__(256) void flash_kernel(
    const u16* __restrict__ Qu, const u16* __restrict__ Kf,
    const u16* __restrict__ Vf, const u32* __restrict__ bdq,
    const int* __restrict__ mask, const int* __restrict__ rowflag,
    u16* __restrict__ Opart, float* __restrict__ Mpart, float* __restrict__ Lpart)
{
  int w = threadIdx.x >> 6, lane = threadIdx.x & 63;
  int g = lane >> 4, li = lane & 15;
  int bh = blockIdx.y; int b = bh >> 3, h = bh & 7;
  int z = blockIdx.z;
  int qb = blockIdx.x*64 + w*16;
  int q = qb + li;

  const u16* qrow = Qu + ((size_t)bh*TT + q)*DHEAD;
  bf16x8 qu0 = *(const bf16x8*)(qrow + 8*g);
  bf16x8 qu1 = *(const bf16x8*)(qrow + 32 + 8*g);

  f32x4 acc[4] = {{0,0,0,0},{0,0,0,0},{0,0,0,0},{0,0,0,0}};
  float mrun = -3e38f, lrun = 0.f;
  int rf = rowflag[b*TT + q];
  bool needmask = (__all(rf) == 0);

  const u16* kfb = Kf + (size_t)bh*128*1024;
  const u16* vfb = Vf + (size_t)bh*128*1024;
  const u32* bdb = bdq + (size_t)bh*(TT/4)*TT;
  const int* maskq = mask + ((size_t)b*TT + q)*TT;

  int kbeg = z * (TT/NSPLIT);
  for (int k0 = kbeg; k0 < kbeg + TT/NSPLIT; k0 += 128){
    // ---- phase 1: issue bd loads for BOTH 64-k sub-tiles, then all QK MFMAs ----
    u32 bdw[8];
#pragma unroll
    for (int i = 0; i < 8; i++)
      bdw[i] = bdb[(size_t)((k0>>2) + 4*i + g)*TT + q];
    f32x4 s[8];
#pragma unroll
    for (int i = 0; i < 8; i++){
      const u16* kp = kfb + (size_t)((k0>>4) + i)*1024 + lane*8;
      f32x4 t_ = {0,0,0,0};
      t_ = MFMA16(*(const bf16x8*)(kp),       qu0, t_);
      t_ = MFMA16(*(const bf16x8*)(kp + 512), qu1, t_);
      s[i] = t_;
    }
#pragma unroll
    for (int i = 0; i < 8; i++){
      f32x2 lo2 = upk2fp8(bdw[i]);
      f32x2 hi2 = upk2fp8(bdw[i] >> 16);
      s[i][0] += lo2[0]; s[i][1] += lo2[1];
      s[i][2] += hi2[0]; s[i][3] += hi2[1];
    }
    if (needmask && !rf){
#pragma unroll
      for (int i = 0; i < 8; i++){
        s32x4 mv = *(const s32x4*)(maskq + k0 + 16*i + 4*g);
#pragma unroll
        for (int r = 0; r < 4; r++)
          if (mv[r] == 0) s[i][r] = -3e38f;
      }
    }
    // ---- phase 2: softmax + PV per 64-k sub-tile (serial in mrun; MFMA/loads already issued) ----
#pragma unroll
    for (int sub = 0; sub < 2; sub++){
      f32x4* ss = &s[4*sub];
      float tmloc = ss[0][0];
#pragma unroll
      for (int kc = 0; kc < 4; kc++)
#pragma unroll
        for (int r = 0; r < 4; r++) tmloc = fmaxf(tmloc, ss[kc][r]);
      float mn;
      if (__all(tmloc <= mrun)){
        mn = mrun;                      // exact defer: no shfl, no rescale
      } else {
        float tm = fmaxf(tmloc, __shfl_xor(tmloc, 16));
        tm = fmaxf(tm, __shfl_xor(tm, 32));
        mn = fmaxf(mrun, tm);
        float fscq = __builtin_amdgcn_exp2f(mrun - mn);
        mrun = mn;
        lrun *= fscq;
#pragma unroll
        for (int r = 0; r < 4; r++){
          float fr = __shfl(fscq, 4*g + r);
          acc[0][r] *= fr; acc[1][r] *= fr; acc[2][r] *= fr; acc[3][r] *= fr;
        }
      }
      float ps = 0.f;
      s16x4 pk[4];
#pragma unroll
      for (int kc = 0; kc < 4; kc++){
        float p0 = __builtin_amdgcn_exp2f(ss[kc][0] - mn);
        float p1 = __builtin_amdgcn_exp2f(ss[kc][1] - mn);
        float p2 = __builtin_amdgcn_exp2f(ss[kc][2] - mn);
        float p3 = __builtin_amdgcn_exp2f(ss[kc][3] - mn);
        ps += (p0 + p1) + (p2 + p3);
        union { u32 w[2]; s16x4 v; } u_;
        u_.w[0] = cvtpk(p0, p1);
        u_.w[1] = cvtpk(p2, p3);
        pk[kc] = u_.v;
      }
      ps += __shfl_xor(ps, 16);
      ps += __shfl_xor(ps, 32);
      lrun += ps;
      int kb = (k0 >> 4) + 4*sub;
#pragma unroll
      for (int kc = 0; kc < 4; kc++){
        const u16* vp = vfb + (size_t)(kb + kc)*1024 + lane*8;
        bf16x8 v0 = *(const bf16x8*)(vp);
        bf16x8 v1 = *(const bf16x8*)(vp + 512);
        s16x8 w0 = (s16x8)v0, w1 = (s16x8)v1;
        acc[0] = MFMA_PV(pk[kc], __builtin_shufflevector(w0, w0, 0,1,2,3), acc[0]);
        acc[1] = MFMA_PV(pk[kc], __builtin_shufflevector(w0, w0, 4,5,6,7), acc[1]);
        acc[2] = MFMA_PV(pk[kc], __builtin_shufflevector(w1, w1, 0,1,2,3), acc[2]);
        acc[3] = MFMA_PV(pk[kc], __builtin_shufflevector(w1, w1, 4,5,6,7), acc[3]);
      }
    }
  }
#pragma unroll
  for (int r = 0; r < 4; r++){
    size_t o = ((size_t)(b*TT + qb + 4*g + r)*NSPLIT + z)*DMODEL + h*DHEAD + li;
    Opart[o]      = f2b(acc[0][r]);
    Opart[o + 16] = f2b(acc[1][r]);
    Opart[o + 32] = f2b(acc[2][r]);
    Opart[o + 48] = f2b(acc[3][r]);
  }
  if (lane < 16){
    size_t mo = ((size_t)(b*TT + qb + li)*NSPLIT + z)*NHEADS + h;
    Mpart[mo] = mrun;
    Lpart[mo] = lrun;
  }
}

// ---------------- merge splits + per-token absmax quant of H (fragment-layout output) ----------------
__global__ __launch_bounds__(256) void merge_kernel(
    const u16* __restrict__ Opart, const float* __restrict__ Mpart, const float* __restrict__ Lpart,
    const int* __restrict__ bwp, u16* __restrict__ xq, float* __restrict__ stok)
{
  int tok = blockIdx.x, tid = threadIdx.x;
  __shared__ float scl[NSPLIT][NHEADS];
  if (tid < NHEADS){
    int h = tid;
    float ms[NSPLIT], ls[NSPLIT];
#pragma unroll
    for (int s = 0; s < NSPLIT; s++){
      ms[s] = Mpart[((size_t)tok*NSPLIT + s)*NHEADS + h];
      ls[s] = Lpart[((size_t)tok*NSPLIT + s)*NHEADS + h];
    }
    float mst = ms[0];
#pragma unroll
    for (int s = 1; s < NSPLIT; s++) mst = fmaxf(mst, ms[s]);
    float sc_[NSPLIT]; float lst = 0.f;
#pragma unroll
    for (int s = 0; s < NSPLIT; s++){
      sc_[s] = __builtin_amdgcn_exp2f(ms[s] - mst);
      lst += ls[s]*sc_[s];
    }
    float inv = (lst > 0.f) ? 1.0f/lst : 0.f;
#pragma unroll
    for (int s = 0; s < NSPLIT; s++) scl[s][h] = sc_[s]*inv;
  }
  __syncthreads();
  float hv[2];
#pragma unroll
  for (int j = 0; j < 2; j++){
    int idx = tid + 256*j;
    int h = idx >> 6;
    float a = 0.f;
#pragma unroll
    for (int s = 0; s < NSPLIT; s++)
      a += b2f(Opart[((size_t)tok*NSPLIT + s)*DMODEL + idx]) * scl[s][h];
    hv[j] = a;
  }
  __shared__ float red[256];
  red[tid] = fmaxf(fabsf(hv[0]), fabsf(hv[1])); __syncthreads();
  for (int o=128;o>0;o>>=1){ if(tid<o) red[tid]=fmaxf(red[tid],red[tid+o]); __syncthreads(); }
  float amax = red[0];
  float Qb = (float)((1 << (bwp[0]-1)) - 1);
  float xs = Qb / (amax + 1e-5f);
  if (tid == 0) stok[tok] = (amax + 1e-5f) / Qb;
#pragma unroll
  for (int j = 0; j < 2; j++){
    int idx = tid + 256*j;
    float qv = fminf(fmaxf(rintf(hv[j] * xs), -Qb), Qb);
    xq[fidx(tok, idx)] = f2b(qv);
  }
}

// ---------------- launch ----------------
extern "C" void kernel_launch(void* const* d_in, const int* in_sizes, int n_in,
                              void* d_out, int out_size, void* d_ws, size_t ws_size,
                              hipStream_t stream) {
  const float* x    = (const float*)d_in[0];
  const int*   mask = (const int*)  d_in[1];
  const float* pos  = (const float*)d_in[2];
  const float* lng  = (const float*)d_in[3];
  const float* lnb  = (const float*)d_in[4];
  const float* Wq   = (const float*)d_in[5];
  const float* bq   = (const float*)d_in[6];
  const float* Wk   = (const float*)d_in[7];
  const float* bk   = (const float*)d_in[8];
  const float* Wv   = (const float*)d_in[9];
  const float* bv   = (const float*)d_in[10];
  const float* Wp   = (const float*)d_in[11];
  const float* bp   = (const float*)d_in[12];
  const float* Wo   = (const float*)d_in[13];
  const float* bo   = (const float*)d_in[14];
  const float* pbu  = (const float*)d_in[15];
  const float* pbv  = (const float*)d_in[16];
  const int*   bwp  = (const int*)  d_in[17];
  float* out = (float*)d_out;

  char* wsb = (char*)d_ws;
  size_t off = 0;
  auto alloc = [&](size_t nbytes)->char* {
    char* p = wsb + off;
    off = (off + nbytes + 255) & ~(size_t)255;
    return p;
  };
  float* partial = (float*)alloc(5*64*sizeof(float));
  float* wsv     = (float*)alloc(5*sizeof(float));
  u16*   wt      = (u16*)  alloc((size_t)5*262144*2);
  float* stok_y  = (float*)alloc(MTOK*sizeof(float));
  float* stok_p  = (float*)alloc(TT*sizeof(float));
  u16*   Qu      = (u16*)  alloc((size_t)16*TT*DHEAD*2);
  u16*   Qv      = (u16*)  alloc((size_t)16*TT*DHEAD*2);
  u16*   Kf      = (u16*)  alloc((size_t)16*TT*DHEAD*2);
  u16*   Vf      = (u16*)  alloc((size_t)16*TT*DHEAD*2);
  // pool: xq_y + xq_p + Pf live before flash; Opart (aliased) live after
  u16*   pool    = (u16*)  alloc((size_t)MTOK*NSPLIT*DMODEL*2);   // 16.8 MB
  u16*   xq_y    = pool;
  u16*   xq_p    = pool + (size_t)MTOK*DMODEL;
  u16*   Pf      = xq_p + (size_t)TT*DMODEL;
  u16*   Opart   = pool;
  float* Mpart   = (float*)alloc((size_t)MTOK*NSPLIT*NHEADS*sizeof(float));
  float* Lpart   = (float*)alloc((size_t)MTOK*NSPLIT*NHEADS*sizeof(float));
  u16*   xq_H    = (u16*)  alloc((size_t)MTOK*DMODEL*2);
  float* stok_H  = (float*)alloc(MTOK*sizeof(float));
  int*   rowflag = (int*)  alloc(MTOK*sizeof(int));
  u32*   bdq     = (u32*)  alloc((size_t)16*(TT/4)*TT*4);         // 67 MB fp8-packed
  if (off > ws_size) return;  // clean fail if workspace too small

  // weight prep
  wprep1_kernel<<<dim3(64,5), 256, 0, stream>>>(Wq, Wk, Wv, Wp, Wo, partial);
  wprep2_kernel<<<dim3(256,5), 256, 0, stream>>>(Wq, Wk, Wv, Wp, Wo, partial, wsv, wt);
  // activations
  lnq_kernel<<<MTOK, 256, 0, stream>>>(x, lng, lnb, bwp, xq_y, stok_y);
  quant_kernel<<<TT, 256, 0, stream>>>(pos, bwp, xq_p, stok_p);
  maskflag_kernel<<<MTOK, 256, 0, stream>>>(mask, rowflag);
  // projections: merged QKV, then P (fragment layout)
  qkvgemm_kernel<<<dim3(24,64), 256, 0, stream>>>(xq_y, wt, stok_y, wsv, bq, bk, bv, pbu, pbv,
                                                  Qu, Qv, Kf, Vf);
  qgemm_kernel<2><<<dim3(16,32), 256, 0, stream>>>(xq_p, wt + (size_t)3*262144, stok_p, wsv, 3, bp, 3,
                                                   Pf, nullptr, nullptr, nullptr);
  // rel-pos matrix: output-tiled, f32 LDS transpose, fp8-packed lined HBM writes
  bd_kernel<<<dim3(32,32,16), 256, 0, stream>>>(Qv, Pf, bdq);
  // fused attention, split-K, 2-deep k-tile pipeline
  flash_kernel<<<dim3(32,16,NSPLIT), 256, 0, stream>>>(Qu, Kf, Vf, bdq, mask, rowflag,
                                                       Opart, Mpart, Lpart);
  // merge splits + quantize H
  merge_kernel<<<MTOK, 256, 0, stream>>>(Opart, Mpart, Lpart, bwp, xq_H, stok_H);
  // output projection (+ residual + seq mask)
  qgemm_kernel<2><<<dim3(16,64), 256, 0, stream>>>(xq_H, wt + (size_t)4*262144, stok_H, wsv, 4, bo, 4,
                                                   nullptr, out, x, mask);
}

// Round 12
// 175.341 us; speedup vs baseline: 1.1618x; 1.0347x over previous
//
#include <hip/hip_runtime.h>
#include <math.h>

#define TT 2048
#define DMODEL 512
#define NHEADS 8
#define DHEAD 64
#define NBATCH 2
#define MTOK (NBATCH*TT)
#define NSPLIT 2
#define SC 0.18033688011112042f   // 0.125 * log2(e): fold 1/sqrt(Dh) and exp->exp2
#define PADQ 68                   // LDS row pad (f32 words): 16B-aligned rows, spread banks

typedef unsigned short u16;
typedef unsigned int u32;
typedef __bf16 bf16x8 __attribute__((ext_vector_type(8)));
typedef float f32x4 __attribute__((ext_vector_type(4)));
typedef float f32x2 __attribute__((ext_vector_type(2)));
typedef short s16x4 __attribute__((ext_vector_type(4)));
typedef short s16x8 __attribute__((ext_vector_type(8)));
typedef unsigned short u16x4 __attribute__((ext_vector_type(4)));
typedef unsigned int u32x4 __attribute__((ext_vector_type(4)));
typedef int s32x4 __attribute__((ext_vector_type(4)));

#define MFMA16(a,b,c) __builtin_amdgcn_mfma_f32_16x16x32_bf16(a,b,c,0,0,0)
#define MFMA_PV(a,b,c) __builtin_amdgcn_mfma_f32_16x16x16bf16_1k(a,b,c,0,0,0)

__device__ __forceinline__ u16 f2b(float f){
  u32 x = __float_as_uint(f);
  x = x + 0x7fffu + ((x >> 16) & 1u);
  return (u16)(x >> 16);
}
__device__ __forceinline__ float b2f(u16 u){
  return __uint_as_float(((u32)u) << 16);
}
__device__ __forceinline__ u32 cvtpk(float lo, float hi){
  u32 d; asm("v_cvt_pk_bf16_f32 %0, %1, %2" : "=v"(d) : "v"(lo), "v"(hi)); return d;
}
// fp8 e4m3 (OCP) pack/unpack via HW converts
__device__ __forceinline__ u32 pk4fp8(float a, float b, float c, float d){
  u32 lo, hi;
  asm("v_cvt_pk_fp8_f32 %0, %1, %2" : "=v"(lo) : "v"(a), "v"(b));
  asm("v_cvt_pk_fp8_f32 %0, %1, %2" : "=v"(hi) : "v"(c), "v"(d));
  return (lo & 0xFFFFu) | (hi << 16);
}
__device__ __forceinline__ f32x2 upk2fp8(u32 v){
  f32x2 r;
  asm("v_cvt_pk_f32_fp8 %0, %1" : "=v"(r) : "v"(v));
  return r;
}
// MFMA fragment layout index (16-row x 32-col tiles, lane*8 contiguous per wave):
__device__ __forceinline__ size_t fidx(int t, int d){
  return ((size_t)((t>>4)*16 + (d>>5)))*512
       + (size_t)(((((d>>3)&3)*16) + (t&15))*8 + (d&7));
}

// ---------------- weight prep: ws = mean|W| + 1e-5, ternary Wt (fragment layout) ----------------
__global__ __launch_bounds__(256) void wprep1_kernel(
    const float* __restrict__ W0, const float* __restrict__ W1,
    const float* __restrict__ W2, const float* __restrict__ W3,
    const float* __restrict__ W4, float* __restrict__ partial)
{
  int widx = blockIdx.y;
  const float* W = (widx==0)?W0:(widx==1)?W1:(widx==2)?W2:(widx==3)?W3:W4;
  size_t base = (size_t)blockIdx.x * 4096;
  int tid = threadIdx.x, w = tid >> 6, lane = tid & 63;
  float s = 0.f;
  for (int i = tid; i < 4096; i += 256) s += fabsf(W[base + i]);
#pragma unroll
  for (int o = 1; o < 64; o <<= 1) s += __shfl_xor(s, o);
  __shared__ float red[4];
  if (lane == 0) red[w] = s;
  __syncthreads();
  if (tid == 0) partial[widx*64 + blockIdx.x] = red[0]+red[1]+red[2]+red[3];
}

__global__ __launch_bounds__(256) void wprep2_kernel(
    const float* __restrict__ W0, const float* __restrict__ W1,
    const float* __restrict__ W2, const float* __restrict__ W3,
    const float* __restrict__ W4, const float* __restrict__ partial,
    float* __restrict__ wsv, u16* __restrict__ wt)
{
  int widx = blockIdx.y;
  const float* W = (widx==0)?W0:(widx==1)?W1:(widx==2)?W2:(widx==3)?W3:W4;
  __shared__ float red[64];
  int tid = threadIdx.x;
  if (tid < 64) red[tid] = partial[widx*64 + tid];
  __syncthreads();
  for (int o = 32; o > 0; o >>= 1){ if (tid < o) red[tid] += red[tid+o]; __syncthreads(); }
  float ws = red[0] * (1.0f/262144.0f) + 1e-5f;
  if (blockIdx.x == 0 && tid == 0) wsv[widx] = ws;
  int base = blockIdx.x * 1024;
  for (int i = tid; i < 1024; i += 256){
    int idx = base + i;
    int n = idx >> 9, k = idx & 511;
    float v = rintf(W[idx] / ws);
    v = fminf(fmaxf(v, -1.f), 1.f);
    wt[(size_t)widx*262144 + fidx(n, k)] = f2b(v);
  }
}

// ---------------- LayerNorm + activation quant (per token, fragment-layout output, shfl-reduce) ----------------
__global__ __launch_bounds__(256) void lnq_kernel(
    const float* __restrict__ x, const float* __restrict__ g, const float* __restrict__ b,
    const int* __restrict__ bwp, u16* __restrict__ xq, float* __restrict__ stok)
{
  int t = blockIdx.x;
  const float* xr = x + (size_t)t * DMODEL;
  int tid = threadIdx.x, w = tid >> 6, lane = tid & 63;
  float v0 = xr[tid], v1 = xr[tid + 256];
  float s1 = v0 + v1, s2 = v0*v0 + v1*v1;
#pragma unroll
  for (int o = 1; o < 64; o <<= 1){ s1 += __shfl_xor(s1, o); s2 += __shfl_xor(s2, o); }
  __shared__ float pa[4], pb[4], pm[4];
  if (lane == 0){ pa[w] = s1; pb[w] = s2; }
  __syncthreads();
  float sum = pa[0]+pa[1]+pa[2]+pa[3];
  float sqs = pb[0]+pb[1]+pb[2]+pb[3];
  float mu  = sum * (1.0f/512.0f);
  float var = sqs * (1.0f/512.0f) - mu*mu;
  float rs = rsqrtf(var + 1e-5f);
  float y0 = (v0 - mu)*rs*g[tid] + b[tid];
  float y1 = (v1 - mu)*rs*g[tid+256] + b[tid+256];
  float am = fmaxf(fabsf(y0), fabsf(y1));
#pragma unroll
  for (int o = 1; o < 64; o <<= 1) am = fmaxf(am, __shfl_xor(am, o));
  if (lane == 0) pm[w] = am;
  __syncthreads();
  float amax = fmaxf(fmaxf(pm[0], pm[1]), fmaxf(pm[2], pm[3]));
  float Qb = (float)((1 << (bwp[0]-1)) - 1);
  float xs = Qb / (amax + 1e-5f);
  if (tid == 0) stok[t] = (amax + 1e-5f) / Qb;
  float q0 = fminf(fmaxf(rintf(y0 * xs), -Qb), Qb);
  float q1 = fminf(fmaxf(rintf(y1 * xs), -Qb), Qb);
  xq[fidx(t, tid)]       = f2b(q0);
  xq[fidx(t, tid + 256)] = f2b(q1);
}

// ---------------- activation quant only (per token, fragment-layout output, shfl-reduce) ----------------
__global__ __launch_bounds__(256) void quant_kernel(
    const float* __restrict__ src, const int* __restrict__ bwp,
    u16* __restrict__ xq, float* __restrict__ stok)
{
  int t = blockIdx.x;
  const float* xr = src + (size_t)t * DMODEL;
  int tid = threadIdx.x, w = tid >> 6, lane = tid & 63;
  float v0 = xr[tid], v1 = xr[tid + 256];
  float am = fmaxf(fabsf(v0), fabsf(v1));
#pragma unroll
  for (int o = 1; o < 64; o <<= 1) am = fmaxf(am, __shfl_xor(am, o));
  __shared__ float pm[4];
  if (lane == 0) pm[w] = am;
  __syncthreads();
  float amax = fmaxf(fmaxf(pm[0], pm[1]), fmaxf(pm[2], pm[3]));
  float Qb = (float)((1 << (bwp[0]-1)) - 1);
  float xs = Qb / (amax + 1e-5f);
  if (tid == 0) stok[t] = (amax + 1e-5f) / Qb;
  float q0 = fminf(fmaxf(rintf(v0 * xs), -Qb), Qb);
  float q1 = fminf(fmaxf(rintf(v1 * xs), -Qb), Qb);
  xq[fidx(t, tid)]       = f2b(q0);
  xq[fidx(t, tid + 256)] = f2b(q1);
}

// ---------------- mask row flags: 1 if whole row nonzero (vectorized + wave __all) ----------------
__global__ __launch_bounds__(256) void maskflag_kernel(const int* __restrict__ mask, int* __restrict__ rowflag){
  int row = blockIdx.x; // b*TT + q
  int tid = threadIdx.x, w = tid >> 6, lane = tid & 63;
  const s32x4* mr = (const s32x4*)(mask + (size_t)row * TT);
  s32x4 a = mr[tid], b2 = mr[tid + 256];
  bool ok = (a[0]!=0)&(a[1]!=0)&(a[2]!=0)&(a[3]!=0)&(b2[0]!=0)&(b2[1]!=0)&(b2[2]!=0)&(b2[3]!=0);
  int wok = __all(ok);
  __shared__ int red[4];
  if (lane == 0) red[w] = wok;
  __syncthreads();
  if (tid == 0) rowflag[row] = red[0] & red[1] & red[2] & red[3];
}

// ---------------- merged QKV quantized GEMM (N = 1536 over concat Wq|Wk|Wv, coalesced fragments) ----------------
__global__ __launch_bounds__(256) void qkvgemm_kernel(
    const u16* __restrict__ Af, const u16* __restrict__ wtf,
    const float* __restrict__ stok, const float* __restrict__ wsv,
    const float* __restrict__ bq, const float* __restrict__ bk, const float* __restrict__ bv,
    const float* __restrict__ pbu, const float* __restrict__ pbv,
    u16* __restrict__ Qu, u16* __restrict__ Qv, u16* __restrict__ Kf, u16* __restrict__ Vf)
{
  int w = threadIdx.x >> 6, lane = threadIdx.x & 63;
  int g = lane >> 4, li = lane & 15;
  int mb = blockIdx.y*64 + w*16;
  int nb = blockIdx.x*64;           // 0..1535, widx constant per block
  int widx = nb >> 9;
  int ntb = (nb & 511) >> 4;
  f32x4 acc[4] = {{0,0,0,0},{0,0,0,0},{0,0,0,0},{0,0,0,0}};
  const u16* Ab = Af + (size_t)(mb >> 4)*16*512 + lane*8;
  const u16* Bb = wtf + (size_t)widx*262144 + (size_t)ntb*16*512 + lane*8;
  for (int kb = 0; kb < 16; kb++){
    bf16x8 a = *(const bf16x8*)(Ab + kb*512);
#pragma unroll
    for (int f = 0; f < 4; f++){
      bf16x8 bb = *(const bf16x8*)(Bb + (f*16 + kb)*512);
      acc[f] = MFMA16(a, bb, acc[f]);
    }
  }
  float ws = wsv[widx];
  const float* bias = (widx==0)?bq:(widx==1)?bk:bv;
  float sc[4];
#pragma unroll
  for (int r=0;r<4;r++) sc[r] = ws * stok[mb + 4*g + r];
#pragma unroll
  for (int f=0;f<4;f++){
    int n = nb + 16*f + li;
    int nq = n & 511;
    float bn = bias[nq];
#pragma unroll
    for (int r=0;r<4;r++){
      int m = mb + 4*g + r;
      float val = acc[f][r]*sc[r] + bn;
      int bb_ = m >> 11, t = m & (TT-1); int h = nq >> 6, d = nq & 63;
      int bh = bb_*NHEADS + h;
      if (widx == 0){
        size_t o = (((size_t)bh)*TT + t)*DHEAD + d;
        Qu[o] = f2b((val + pbu[nq])*SC);
        Qv[o] = f2b(val + pbv[nq]);
      } else if (widx == 1){
        size_t o = (((size_t)bh*128 + (t>>4))*2 + (d>>5))*512
                 + (size_t)((((d>>3)&3)*16 + (t&15))*8 + (d&7));
        Kf[o] = f2b(val);
      } else {
        size_t o = (((size_t)bh*128 + (t>>4))*2 + (d>>5))*512
                 + (size_t)(((((t>>2)&3)*16) + (d&15))*8 + (((d>>4)&1)*4) + (t&3));
        Vf[o] = f2b(val);
      }
    }
  }
}

// ---------------- quantized GEMM (narrow tiles, NF cols of 16 per wave, coalesced fragments) ----------------
// modes: 3=P -> Pf fragment layout (Kf-style, per head)   4=O->f32 d_out = x + val*maskrow
template<int NF>
__global__ __launch_bounds__(256) void qgemm_kernel(
    const u16* __restrict__ Af, const u16* __restrict__ Wtf,
    const float* __restrict__ stok, const float* __restrict__ wsv, int widx,
    const float* __restrict__ bias, int mode,
    u16* __restrict__ outA, float* __restrict__ outF,
    const float* __restrict__ xin, const int* __restrict__ mask)
{
  int w = threadIdx.x >> 6, lane = threadIdx.x & 63;
  int g = lane >> 4, li = lane & 15;
  int mb = blockIdx.y*64 + w*16;
  int nb = blockIdx.x*(16*NF);
  f32x4 acc[NF];
#pragma unroll
  for (int f=0; f<NF; f++) acc[f] = (f32x4){0,0,0,0};
  const u16* Ab = Af + (size_t)(mb >> 4)*16*512 + lane*8;
  const u16* Bb = Wtf + (size_t)(nb >> 4)*16*512 + lane*8;
  for (int kb = 0; kb < 16; kb++){
    bf16x8 a = *(const bf16x8*)(Ab + kb*512);
#pragma unroll
    for (int f = 0; f < NF; f++){
      bf16x8 bb = *(const bf16x8*)(Bb + (f*16 + kb)*512);
      acc[f] = MFMA16(a, bb, acc[f]);
    }
  }
  float ws = wsv[widx];
  float sc[4];
#pragma unroll
  for (int r=0;r<4;r++) sc[r] = ws * stok[mb + 4*g + r];
#pragma unroll
  for (int f=0;f<NF;f++){
    int n = nb + 16*f + li;
    float bn = bias[n];
#pragma unroll
    for (int r=0;r<4;r++){
      int m = mb + 4*g + r;
      float val = acc[f][r]*sc[r] + bn;
      if (mode == 3){
        int h = n >> 6, d = n & 63;
        size_t o = (((size_t)h*128 + (m>>4))*2 + (d>>5))*512
                 + (size_t)((((d>>3)&3)*16 + (m&15))*8 + (d&7));
        outA[o] = f2b(val);
      } else {
        int bb_ = m >> 11, t = m & (TT-1);
        float mv = (float)mask[((size_t)bb_*TT + t)*TT];
        outF[(size_t)m*DMODEL + n] = xin[(size_t)m*DMODEL + n] + val*mv;
      }
    }
  }
}

// ---------------- bd kernel: output-tiled rel-shifted GEMM, f32 LDS transpose, fp8 lined writes ----------------
// XCD-aware 1-D grid: each XCD (blockIdx%8 heuristic) owns 2 bh with the SAME head h, processed
// contiguously -> Pf head + Qv slice stay resident in that XCD's private L2.
__global__ __launch_bounds__(256) void bd_kernel(
    const u16* __restrict__ Qv, const u16* __restrict__ Pf, u32* __restrict__ bdq)
{
  __shared__ float lds[64*PADQ];
  int L = blockIdx.x;
  int m = L >> 3;
  int bh = (L & 7) + 8*(m >> 10);
  int inner = m & 1023;
  int qb = (inner & 31) << 6;
  int k0 = (inner >> 5) << 6;
  int h = bh & 7;
  int tid = threadIdx.x;
  int w = tid >> 6, lane = tid & 63;
  int g = lane >> 4, li = lane & 15;
  int qt = qb + 16*w;
  // diagonal k == q+1 (the only slot neither triangle writes)
  if (tid < 64){
    int kd = qb + tid + 1 - k0;
    if ((unsigned)kd < 64u) lds[kd*PADQ + tid] = 0.f;
  }
  const u16* Pbh = Pf + (size_t)h*128*1024;
  const u16* Qbh = Qv + (size_t)bh*TT*DHEAD;
  int qp = 16*w + 4*g;
  // ---- lower triangle: bd_s[q][k] = R[q][j], j = k + TT-1 - q ----
  {
    const u16* qr = Qbh + (size_t)(qt + li)*DHEAD;
    bf16x8 a0 = *(const bf16x8*)(qr + 8*g);
    bf16x8 a1 = *(const bf16x8*)(qr + 32 + 8*g);
    int dkq = k0 - qt;
    for (int i = 0; i < 5; i++){
      if (dkq + 16*i > 15) break;
      int jt = k0 + TT - 16 - qt + 16*i;
      int j = jt + li;
      bool jok = (j <= TT-1);
      int jc = jok ? j : (TT-1);
      const u16* pr = Pbh + (size_t)(jc>>4)*1024 + (size_t)((g*16 + (jc&15))*8);
      f32x4 c = {0,0,0,0};
      c = MFMA16(a0, *(const bf16x8*)(pr),       c);
      c = MFMA16(a1, *(const bf16x8*)(pr + 512), c);
      int kp = 16*i - 15 + li + 4*g;
#pragma unroll
      for (int r = 0; r < 4; r++){
        int kpr = kp + r;
        if (jok && kpr >= 0 && kpr < 64)
          lds[kpr*PADQ + qp + r] = c[r]*SC;
      }
    }
  }
  // ---- upper triangle: bd_s[q][k] = R[q+1][j2], j2 = k - q - 2 ----
  {
    int q2r = qt + 1 + li; if (q2r > TT-1) q2r = TT-1;
    const u16* qr = Qbh + (size_t)q2r*DHEAD;
    bf16x8 a0 = *(const bf16x8*)(qr + 8*g);
    bf16x8 a1 = *(const bf16x8*)(qr + 32 + 8*g);
    int dqk = qt - k0;
    for (int i = 5; i >= 0; i--){
      if (16*i < dqk + 17) break;
      int jt2 = k0 - qt - 32 + 16*i;
      int j2 = jt2 + li;
      bool jok = (j2 >= 0);
      int jc = jok ? j2 : 0;
      const u16* pr = Pbh + (size_t)(jc>>4)*1024 + (size_t)((g*16 + (jc&15))*8);
      f32x4 c = {0,0,0,0};
      c = MFMA16(a0, *(const bf16x8*)(pr),       c);
      c = MFMA16(a1, *(const bf16x8*)(pr + 512), c);
      int kp = 16*i - 30 + li + 4*g;
#pragma unroll
      for (int r = 0; r < 4; r++){
        int kpr = kp + r;
        if (jok && kpr >= 0 && kpr < 64)
          lds[kpr*PADQ + qp + r] = c[r]*SC;
      }
    }
  }
  __syncthreads();
  // ---- writeout: fp8-pack from f32, bdq[k>>2][q], contiguous 256B runs per 16-thread group ----
  {
    int kq = tid >> 4, qg = tid & 15;
    f32x4 v[4];
#pragma unroll
    for (int kk = 0; kk < 4; kk++)
      v[kk] = *(const f32x4*)(&lds[(4*kq + kk)*PADQ + 4*qg]);
    u32x4 o4;
#pragma unroll
    for (int qq = 0; qq < 4; qq++)
      o4[qq] = pk4fp8(v[0][qq], v[1][qq], v[2][qq], v[3][qq]);
    u32* ob = bdq + (size_t)bh*(TT/4)*TT + ((size_t)((k0>>2) + kq)*TT + qb + 4*qg);
    *(u32x4*)ob = o4;
  }
}

// ---------------- split-K flash attention (coalesced fragment layouts, fp8 bd, zero-LDS, zero-barrier) ----------------
__global__ __launch_bounds__(256) void flash_kernel(
    const u16* __restrict__ Qu, const u16* __restrict__ Kf,
    const u16* __restrict__ Vf, const u32* __restrict__ bdq,
    const int* __restrict__ mask, const int* __restrict__ rowflag,
    u16* __restrict__ Opart, float* __restrict__ Mpart, float* __restrict__ Lpart)
{
  int w = threadIdx.x >> 6, lane = threadIdx.x & 63;
  int g = lane >> 4, li = lane & 15;
  int bh = blockIdx.y; int b = bh >> 3, h = bh & 7;
  int z = blockIdx.z;
  int qb = blockIdx.x*64 + w*16;
  int q = qb + li;

  const u16* qrow = Qu + ((size_t)bh*TT + q)*DHEAD;
  bf16x8 qu0 = *(const bf16x8*)(qrow + 8*g);
  bf16x8 qu1 = *(const bf16x8*)(qrow + 32 + 8*g);

  f32x4 acc[4] = {{0,0,0,0},{0,0,0,0},{0,0,0,0},{0,0,0,0}};
  float mrun = -3e38f, lrun = 0.f;
  int rf = rowflag[b*TT + q];
  bool needmask = (__all(rf) == 0);

  const u16* kfb = Kf + (size_t)bh*128*1024;
  const u16* vfb = Vf + (size_t)bh*128*1024;
  const u32* bdb = bdq + (size_t)bh*(TT/4)*TT;
  const int* maskq = mask + ((size_t)b*TT + q)*TT;

  int kbeg = z * (TT/NSPLIT);
  for (int k0 = kbeg; k0 < kbeg + TT/NSPLIT; k0 += 64){
    int kb = k0 >> 4;
    f32x4 s[4];
#pragma unroll
    for (int kc = 0; kc < 4; kc++){
      const u16* kp = kfb + (size_t)(kb + kc)*1024 + lane*8;
      f32x4 t_ = {0,0,0,0};
      t_ = MFMA16(*(const bf16x8*)(kp),       qu0, t_);
      t_ = MFMA16(*(const bf16x8*)(kp + 512), qu1, t_);
      s[kc] = t_;
    }
#pragma unroll
    for (int kc = 0; kc < 4; kc++){
      u32 wb = bdb[(size_t)((k0>>2) + 4*kc + g)*TT + q];
      f32x2 lo2 = upk2fp8(wb);
      f32x2 hi2 = upk2fp8(wb >> 16);
      s[kc][0] += lo2[0]; s[kc][1] += lo2[1];
      s[kc][2] += hi2[0]; s[kc][3] += hi2[1];
    }
    if (needmask && !rf){
#pragma unroll
      for (int kc = 0; kc < 4; kc++){
        s32x4 mv = *(const s32x4*)(maskq + k0 + 16*kc + 4*g);
#pragma unroll
        for (int r = 0; r < 4; r++)
          if (mv[r] == 0) s[kc][r] = -3e38f;
      }
    }
    float tm = s[0][0];
#pragma unroll
    for (int kc = 0; kc < 4; kc++)
#pragma unroll
      for (int r = 0; r < 4; r++) tm = fmaxf(tm, s[kc][r]);
    float mn;
    if (__all(tm <= mrun)){
      mn = mrun;                      // exact defer: no shfl, no rescale
    } else {
      tm = fmaxf(tm, __shfl_xor(tm, 16));
      tm = fmaxf(tm, __shfl_xor(tm, 32));
      mn = fmaxf(mrun, tm);
      float fscq = __builtin_amdgcn_exp2f(mrun - mn);
      mrun = mn;
      lrun *= fscq;
#pragma unroll
      for (int r = 0; r < 4; r++){
        float fr = __shfl(fscq, 4*g + r);
        acc[0][r] *= fr; acc[1][r] *= fr; acc[2][r] *= fr; acc[3][r] *= fr;
      }
    }
    float ps = 0.f;
    s16x4 pk[4];
#pragma unroll
    for (int kc = 0; kc < 4; kc++){
      float p0 = __builtin_amdgcn_exp2f(s[kc][0] - mn);
      float p1 = __builtin_amdgcn_exp2f(s[kc][1] - mn);
      float p2 = __builtin_amdgcn_exp2f(s[kc][2] - mn);
      float p3 = __builtin_amdgcn_exp2f(s[kc][3] - mn);
      ps += (p0 + p1) + (p2 + p3);
      union { u32 w[2]; s16x4 v; } u_;
      u_.w[0] = cvtpk(p0, p1);
      u_.w[1] = cvtpk(p2, p3);
      pk[kc] = u_.v;
    }
    ps += __shfl_xor(ps, 16);
    ps += __shfl_xor(ps, 32);
    lrun += ps;
#pragma unroll
    for (int kc = 0; kc < 4; kc++){
      const u16* vp = vfb + (size_t)(kb + kc)*1024 + lane*8;
      bf16x8 v0 = *(const bf16x8*)(vp);
      bf16x8 v1 = *(const bf16x8*)(vp + 512);
      s16x8 w0 = (s16x8)v0, w1 = (s16x8)v1;
      acc[0] = MFMA_PV(pk[kc], __builtin_shufflevector(w0, w0, 0,1,2,3), acc[0]);
      acc[1] = MFMA_PV(pk[kc], __builtin_shufflevector(w0, w0, 4,5,6,7), acc[1]);
      acc[2] = MFMA_PV(pk[kc], __builtin_shufflevector(w1, w1, 0,1,2,3), acc[2]);
      acc[3] = MFMA_PV(pk[kc], __builtin_shufflevector(w1, w1, 4,5,6,7), acc[3]);
    }
  }
#pragma unroll
  for (int r = 0; r < 4; r++){
    size_t o = ((size_t)(b*TT + qb + 4*g + r)*NSPLIT + z)*DMODEL + h*DHEAD + li;
    Opart[o]      = f2b(acc[0][r]);
    Opart[o + 16] = f2b(acc[1][r]);
    Opart[o + 32] = f2b(acc[2][r]);
    Opart[o + 48] = f2b(acc[3][r]);
  }
  if (lane < 16){
    size_t mo = ((size_t)(b*TT + qb + li)*NSPLIT + z)*NHEADS + h;
    Mpart[mo] = mrun;
    Lpart[mo] = lrun;
  }
}

// ---------------- merge splits + per-token absmax quant of H (fragment-layout output, shfl-reduce) ----------------
__global__ __launch_bounds__(256) void merge_kernel(
    const u16* __restrict__ Opart, const float* __restrict__ Mpart, const float* __restrict__ Lpart,
    const int* __restrict__ bwp, u16* __restrict__ xq, float* __restrict__ stok)
{
  int tok = blockIdx.x, tid = threadIdx.x, w = tid >> 6, lane = tid & 63;
  __shared__ float scl[NSPLIT][NHEADS];
  if (tid < NHEADS){
    int h = tid;
    float ms[NSPLIT], ls[NSPLIT];
#pragma unroll
    for (int s = 0; s < NSPLIT; s++){
      ms[s] = Mpart[((size_t)tok*NSPLIT + s)*NHEADS + h];
      ls[s] = Lpart[((size_t)tok*NSPLIT + s)*NHEADS + h];
    }
    float mst = ms[0];
#pragma unroll
    for (int s = 1; s < NSPLIT; s++) mst = fmaxf(mst, ms[s]);
    float sc_[NSPLIT]; float lst = 0.f;
#pragma unroll
    for (int s = 0; s < NSPLIT; s++){
      sc_[s] = __builtin_amdgcn_exp2f(ms[s] - mst);
      lst += ls[s]*sc_[s];
    }
    float inv = (lst > 0.f) ? 1.0f/lst : 0.f;
#pragma unroll
    for (int s = 0; s < NSPLIT; s++) scl[s][h] = sc_[s]*inv;
  }
  __syncthreads();
  float hv[2];
#pragma unroll
  for (int j = 0; j < 2; j++){
    int idx = tid + 256*j;
    int h = idx >> 6;
    float a = 0.f;
#pragma unroll
    for (int s = 0; s < NSPLIT; s++)
      a += b2f(Opart[((size_t)tok*NSPLIT + s)*DMODEL + idx]) * scl[s][h];
    hv[j] = a;
  }
  float am = fmaxf(fabsf(hv[0]), fabsf(hv[1]));
#pragma unroll
  for (int o = 1; o < 64; o <<= 1) am = fmaxf(am, __shfl_xor(am, o));
  __shared__ float pm[4];
  if (lane == 0) pm[w] = am;
  __syncthreads();
  float amax = fmaxf(fmaxf(pm[0], pm[1]), fmaxf(pm[2], pm[3]));
  float Qb = (float)((1 << (bwp[0]-1)) - 1);
  float xs = Qb / (amax + 1e-5f);
  if (tid == 0) stok[tok] = (amax + 1e-5f) / Qb;
#pragma unroll
  for (int j = 0; j < 2; j++){
    int idx = tid + 256*j;
    float qv = fminf(fmaxf(rintf(hv[j] * xs), -Qb), Qb);
    xq[fidx(tok, idx)] = f2b(qv);
  }
}

// ---------------- launch ----------------
extern "C" void kernel_launch(void* const* d_in, const int* in_sizes, int n_in,
                              void* d_out, int out_size, void* d_ws, size_t ws_size,
                              hipStream_t stream) {
  const float* x    = (const float*)d_in[0];
  const int*   mask = (const int*)  d_in[1];
  const float* pos  = (const float*)d_in[2];
  const float* lng  = (const float*)d_in[3];
  const float* lnb  = (const float*)d_in[4];
  const float* Wq   = (const float*)d_in[5];
  const float* bq   = (const float*)d_in[6];
  const float* Wk   = (const float*)d_in[7];
  const float* bk   = (const float*)d_in[8];
  const float* Wv   = (const float*)d_in[9];
  const float* bv   = (const float*)d_in[10];
  const float* Wp   = (const float*)d_in[11];
  const float* bp   = (const float*)d_in[12];
  const float* Wo   = (const float*)d_in[13];
  const float* bo   = (const float*)d_in[14];
  const float* pbu  = (const float*)d_in[15];
  const float* pbv  = (const float*)d_in[16];
  const int*   bwp  = (const int*)  d_in[17];
  float* out = (float*)d_out;

  char* wsb = (char*)d_ws;
  size_t off = 0;
  auto alloc = [&](size_t nbytes)->char* {
    char* p = wsb + off;
    off = (off + nbytes + 255) & ~(size_t)255;
    return p;
  };
  float* partial = (float*)alloc(5*64*sizeof(float));
  float* wsv     = (float*)alloc(5*sizeof(float));
  u16*   wt      = (u16*)  alloc((size_t)5*262144*2);
  float* stok_y  = (float*)alloc(MTOK*sizeof(float));
  float* stok_p  = (float*)alloc(TT*sizeof(float));
  u16*   Qu      = (u16*)  alloc((size_t)16*TT*DHEAD*2);
  u16*   Qv      = (u16*)  alloc((size_t)16*TT*DHEAD*2);
  u16*   Kf      = (u16*)  alloc((size_t)16*TT*DHEAD*2);
  u16*   Vf      = (u16*)  alloc((size_t)16*TT*DHEAD*2);
  // pool: xq_y + xq_p + Pf live before flash; Opart (aliased) live after
  u16*   pool    = (u16*)  alloc((size_t)MTOK*NSPLIT*DMODEL*2);   // 8.4 MB (NSPLIT=2)
  u16*   xq_y    = pool;
  u16*   xq_p    = pool + (size_t)MTOK*DMODEL;
  u16*   Pf      = xq_p + (size_t)TT*DMODEL;
  u16*   Opart   = pool;
  float* Mpart   = (float*)alloc((size_t)MTOK*NSPLIT*NHEADS*sizeof(float));
  float* Lpart   = (float*)alloc((size_t)MTOK*NSPLIT*NHEADS*sizeof(float));
  u16*   xq_H    = (u16*)  alloc((size_t)MTOK*DMODEL*2);
  float* stok_H  = (float*)alloc(MTOK*sizeof(float));
  int*   rowflag = (int*)  alloc(MTOK*sizeof(int));
  u32*   bdq     = (u32*)  alloc((size_t)16*(TT/4)*TT*4);         // 67 MB fp8-packed
  if (off > ws_size) return;  // clean fail if workspace too small

  // weight prep
  wprep1_kernel<<<dim3(64,5), 256, 0, stream>>>(Wq, Wk, Wv, Wp, Wo, partial);
  wprep2_kernel<<<dim3(256,5), 256, 0, stream>>>(Wq, Wk, Wv, Wp, Wo, partial, wsv, wt);
  // activations
  lnq_kernel<<<MTOK, 256, 0, stream>>>(x, lng, lnb, bwp, xq_y, stok_y);
  quant_kernel<<<TT, 256, 0, stream>>>(pos, bwp, xq_p, stok_p);
  maskflag_kernel<<<MTOK, 256, 0, stream>>>(mask, rowflag);
  // projections: merged QKV, then P (fragment layout)
  qkvgemm_kernel<<<dim3(24,64), 256, 0, stream>>>(xq_y, wt, stok_y, wsv, bq, bk, bv, pbu, pbv,
                                                  Qu, Qv, Kf, Vf);
  qgemm_kernel<2><<<dim3(16,32), 256, 0, stream>>>(xq_p, wt + (size_t)3*262144, stok_p, wsv, 3, bp, 3,
                                                   Pf, nullptr, nullptr, nullptr);
  // rel-pos matrix: XCD-swizzled 1-D grid, f32 LDS transpose, fp8-packed lined HBM writes
  bd_kernel<<<16384, 256, 0, stream>>>(Qv, Pf, bdq);
  // fused attention, split-K
  flash_kernel<<<dim3(32,16,NSPLIT), 256, 0, stream>>>(Qu, Kf, Vf, bdq, mask, rowflag,
                                                       Opart, Mpart, Lpart);
  // merge splits + quantize H
  merge_kernel<<<MTOK, 256, 0, stream>>>(Opart, Mpart, Lpart, bwp, xq_H, stok_H);
  // output projection (+ residual + seq mask)
  qgemm_kernel<2><<<dim3(16,64), 256, 0, stream>>>(xq_H, wt + (size_t)4*262144, stok_H, wsv, 4, bo, 4,
                                                   nullptr, out, x, mask);
}